// Round 18
// baseline (167.501 us; speedup 1.0000x reference)
//
#include <hip/hip_runtime.h>
#include <hip/hip_bf16.h>
#include <stdint.h>

// Round 18: conv -> single-shot blocks (no z-loop). One block = one z-plane's
// 2x2 outputs: 48 independent loads -> one wait -> FMA -> store. 24576 blocks;
// latency hidden by TLP, not intra-wave scheduling (which R5/6/7/15/17 all
// failed to get from the compiler). Trades 3x x-traffic (L2/HBM-absorbed,
// currently at 6-15% HBM) for a 1-latency critical path.
// attn (R16 v_exp) / GEMMs / prep frozen.

typedef _Float16 f16;
typedef _Float16 f16x8 __attribute__((ext_vector_type(8)));
typedef float f32x4 __attribute__((ext_vector_type(4)));
typedef float f32x16 __attribute__((ext_vector_type(16)));
typedef uint32_t u32;
typedef uint32_t u32x4 __attribute__((ext_vector_type(4)));

#define NC 384
#define MFMA16(A_,B_,C_) __builtin_amdgcn_mfma_f32_16x16x32_f16((A_),(B_),(C_),0,0,0)
#define MFMA32(A_,B_,C_) __builtin_amdgcn_mfma_f32_32x32x16_f16((A_),(B_),(C_),0,0,0)

__device__ __forceinline__ void gll16(const void* g, void* l) {
  __builtin_amdgcn_global_load_lds(
      (__attribute__((address_space(1))) void*)g,
      (__attribute__((address_space(3))) void*)l, 16, 0, 0);
}

__device__ __forceinline__ u32 pkf16(float lo, float hi) {
  return __builtin_bit_cast(u32, __builtin_amdgcn_cvt_pkrtz(lo, hi));
}

// ---------------- weight fp32 -> f16 convert (scq folded into wq) ----------------
__global__ __launch_bounds__(256) void cvt_w(
    const float* __restrict__ s0, const float* __restrict__ s1,
    const float* __restrict__ s2, const float* __restrict__ s3,
    f16* __restrict__ d0, f16* __restrict__ d1,
    f16* __restrict__ d2, f16* __restrict__ d3, int n, float scq)
{
  int i = blockIdx.x * 256 + threadIdx.x;
  if (i < n) {
    d0[i] = (f16)(s0[i] * scq);
    d1[i] = (f16)s1[i]; d2[i] = (f16)s2[i]; d3[i] = (f16)s3[i];
  }
}

// ---------------- conv-weight transpose + BN fold ----------------
__global__ __launch_bounds__(384) void cvt_wt(
    const float* __restrict__ wq, const float* __restrict__ wk, const float* __restrict__ wv,
    const float* __restrict__ bqg, const float* __restrict__ bqb,
    const float* __restrict__ bqm, const float* __restrict__ bqv,
    const float* __restrict__ bkg, const float* __restrict__ bkb,
    const float* __restrict__ bkm, const float* __restrict__ bkv,
    const float* __restrict__ bvg, const float* __restrict__ bvb,
    const float* __restrict__ bvm, const float* __restrict__ bvv,
    float* __restrict__ qT, float* __restrict__ kT, float* __restrict__ vT,
    float* __restrict__ betq, float* __restrict__ betk, float* __restrict__ betv)
{
  const int c = threadIdx.x;
  const int t = blockIdx.x;   // 0..26
  const float invq = bqg[c] * rsqrtf(bqv[c] + 1e-5f);
  const float invk = bkg[c] * rsqrtf(bkv[c] + 1e-5f);
  const float invv = bvg[c] * rsqrtf(bvv[c] + 1e-5f);
  qT[t * 384 + c] = wq[c * 27 + t] * invq;
  kT[t * 384 + c] = wk[c * 27 + t] * invk;
  vT[t * 384 + c] = wv[c * 27 + t] * invv;
  if (t == 0) {
    betq[c] = bqb[c] - bqm[c] * invq;
    betk[c] = bkb[c] - bkm[c] * invk;
    betv[c] = bvb[c] - bvm[c] * invv;
  }
}

// ---------------- conv: single-shot per z-plane (no loop) ----------------
// 128 thr (2 waves); grid (64 tiles x 3 c-thirds, 8 b, 16 z).
// Straight-line: 48 guarded loads (3 planes x 4x4) -> compute -> store.
__global__ __launch_bounds__(128) void conv_z1(
    const float* __restrict__ x,
    const float* __restrict__ wqT, const float* __restrict__ wkT, const float* __restrict__ wvT,
    const float* __restrict__ betq_, const float* __restrict__ betk_,
    const float* __restrict__ betv_,
    f16* __restrict__ qout, f16* __restrict__ kout, f16* __restrict__ vout)
{
  const int tile = blockIdx.x / 3, cthird = blockIdx.x % 3;
  const int c = cthird * 128 + threadIdx.x;
  const int th = tile >> 3, tw = tile & 7;
  const int b = blockIdx.y;
  const int z = blockIdx.z;
  const int h0 = th * 2, w0 = tw * 2;

  bool hok[4], wok[4];
#pragma unroll
  for (int a = 0; a < 4; ++a) {
    hok[a] = (unsigned)(h0 - 1 + a) < 16u;
    wok[a] = (unsigned)(w0 - 1 + a) < 16u;
  }
  const float* xb = x + (size_t)b * 4096 * NC + c;

  // 48 independent guarded loads: planes z-1, z, z+1
  float win[3][4][4];
#pragma unroll
  for (int p = 0; p < 3; ++p) {
    const int iz = z - 1 + p;
    const bool zok = (unsigned)iz < 16u;   // block-uniform
#pragma unroll
    for (int a = 0; a < 4; ++a)
#pragma unroll
      for (int e = 0; e < 4; ++e) {
        float v = 0.f;
        if (zok && hok[a] && wok[e])
          v = xb[(size_t)((h0 - 1 + a) * 256 + (w0 - 1 + e) * 16 + iz) * NC];
        win[p][a][e] = v;
      }
  }

  // Q: 2x2 outputs at this z
  float wqr[27];
#pragma unroll
  for (int t = 0; t < 27; ++t) wqr[t] = wqT[t * 384 + c];   // pre-scaled by BN inv
  float aq00 = 0.f, aq01 = 0.f, aq10 = 0.f, aq11 = 0.f;
#pragma unroll
  for (int p = 0; p < 3; ++p)
#pragma unroll
    for (int a = 0; a < 3; ++a)
#pragma unroll
      for (int e = 0; e < 3; ++e) {
        const float cq = wqr[a * 9 + e * 3 + p];
        aq00 += win[p][a][e]         * cq;
        aq01 += win[p][a][e + 1]     * cq;
        aq10 += win[p][a + 1][e]     * cq;
        aq11 += win[p][a + 1][e + 1] * cq;
      }
  const float betq = betq_[c];
  const size_t qb = (size_t)b * 4096;
  qout[(qb + (h0 + 0) * 256 + (w0 + 0) * 16 + z) * NC + c] = (f16)(aq00 + betq);
  qout[(qb + (h0 + 0) * 256 + (w0 + 1) * 16 + z) * NC + c] = (f16)(aq01 + betq);
  qout[(qb + (h0 + 1) * 256 + (w0 + 0) * 16 + z) * NC + c] = (f16)(aq10 + betq);
  qout[(qb + (h0 + 1) * 256 + (w0 + 1) * 16 + z) * NC + c] = (f16)(aq11 + betq);

  // KV at even z (center point (h0, w0): window rows/cols 0..2)
  if ((z & 1) == 0) {
    float ak = 0.f, av = 0.f;
#pragma unroll
    for (int t = 0; t < 27; ++t) {
      const int p = t % 3, e = (t / 3) % 3, a = t / 9;
      const float wv_ = win[p][a][e];
      ak += wv_ * wkT[t * 384 + c];
      av += wv_ * wvT[t * 384 + c];
    }
    const size_t t = (size_t)b * 512 + tile * 8 + (z >> 1);
    kout[t * NC + c] = (f16)(ak + betk_[c]);
    vout[t * NC + c] = (f16)(av + betv_[c]);
  }
}

// ---------------- GEMM (R8 version): gll16 staging + XOR-swizzled LDS ----------------
template<int MODE>
__global__ __launch_bounds__(256) void gemm_bt(
    const f16* __restrict__ A, const f16* __restrict__ Bw,
    void* __restrict__ Cout, const float* __restrict__ bias)
{
  __shared__ f16 As[128 * 64];
  __shared__ f16 Bs[128 * 64];
  const int tid = threadIdx.x;
  const int w = tid >> 6, lane = tid & 63;
  const int g = lane >> 4, q = lane & 15;
  const int wr = w >> 1, wc = w & 1;
  const size_t brow = (size_t)blockIdx.y * 128;
  const int bcol = blockIdx.x * 128;
  const int srow = lane >> 3;
  const int sbb  = (lane & 7) ^ (srow & 7);
  f32x4 acc[4][4] = {};
  for (int kt = 0; kt < 6; ++kt) {
    const int k0 = kt * 64;
#pragma unroll
    for (int j = 0; j < 4; ++j) {
      const int s = w * 4 + j;
      gll16(A  + (brow + (size_t)(s * 8 + srow)) * NC + k0 + sbb * 8, (char*)As + s * 1024);
      gll16(Bw + (size_t)(bcol + s * 8 + srow) * NC + k0 + sbb * 8, (char*)Bs + s * 1024);
    }
    __syncthreads();
#pragma unroll
    for (int ks = 0; ks < 2; ++ks) {
      f16x8 af[4], bfr[4];
      const int bb = ((g + 4 * ks) ^ (q & 7)) * 16;
#pragma unroll
      for (int m = 0; m < 4; ++m) {
        af[m]  = *(const f16x8*)((const char*)As + (wr * 64 + m * 16 + q) * 128 + bb);
        bfr[m] = *(const f16x8*)((const char*)Bs + (wc * 64 + m * 16 + q) * 128 + bb);
      }
#pragma unroll
      for (int m = 0; m < 4; ++m)
#pragma unroll
        for (int n = 0; n < 4; ++n)
          acc[m][n] = MFMA16(af[m], bfr[n], acc[m][n]);
    }
    __syncthreads();
  }
  float bvals[4];
  if (MODE == 2) {
#pragma unroll
    for (int n = 0; n < 4; ++n) bvals[n] = bias[bcol + wc * 64 + n * 16 + q];
  }
#pragma unroll
  for (int m = 0; m < 4; ++m) {
#pragma unroll
    for (int n = 0; n < 4; ++n) {
#pragma unroll
      for (int r = 0; r < 4; ++r) {
        const size_t row = brow + wr * 64 + m * 16 + 4 * g + r;
        const int col = bcol + wc * 64 + n * 16 + q;
        const float v = acc[m][n][r];
        if (MODE == 0) {
          ((f16*)Cout)[row * NC + col] = (f16)v;
        } else if (MODE == 1) {
          const size_t bi = row >> 9, t = row & 511;
          ((f16*)Cout)[(bi * NC + col) * 512 + t] = (f16)v;
        } else {
          ((float*)Cout)[row * NC + col] = v + bvals[n];
        }
      }
    }
  }
}

// ---------------- flash attention (R16): per-half pipeline, v_exp_f32 ----------------
__global__ __launch_bounds__(256) void attn(
    const f16* __restrict__ Qp, const f16* __restrict__ Kp,
    const f16* __restrict__ Vt, f16* __restrict__ O)
{
  __shared__ f16 Ks[2][64 * 64];
  __shared__ f16 Vs[2][64 * 64];
  const int tid = threadIdx.x;
  const int w = tid >> 6, lane = tid & 63;
  const int c = lane & 31, h = lane >> 5;
  const int qt = blockIdx.x, hh = blockIdx.y, b = blockIdx.z;
  const size_t qrow = (size_t)b * 4096 + qt * 128 + w * 32 + c;

  f16x8 qf[4];
#pragma unroll
  for (int ks = 0; ks < 4; ++ks)
    qf[ks] = *(const f16x8*)(Qp + qrow * NC + hh * 64 + ks * 16 + 8 * h);

  f32x16 oa0 = {}, oa1 = {};
  float l_run = 0.f;

  const int r0 = tid >> 3, k0b = tid & 7;
  const int r1 = (tid + 256) >> 3, k1b = tid & 7;
  const f16* ks0 = Kp + ((size_t)b * 512 + r0) * NC + hh * 64 + ((k0b ^ (r0 & 7)) * 8);
  const f16* ks1 = Kp + ((size_t)b * 512 + r1) * NC + hh * 64 + ((k1b ^ (r1 & 7)) * 8);
  const f16* vs0 = Vt + ((size_t)b * NC + hh * 64 + r0) * 512 + ((k0b ^ (r0 & 7)) * 8);
  const f16* vs1 = Vt + ((size_t)b * NC + hh * 64 + r1) * 512 + ((k1b ^ (r1 & 7)) * 8);
  gll16(ks0, (char*)&Ks[0][0] + tid * 16);
  gll16(ks1, (char*)&Ks[0][0] + (tid + 256) * 16);
  gll16(vs0, (char*)&Vs[0][0] + tid * 16);
  gll16(vs1, (char*)&Vs[0][0] + (tid + 256) * 16);

  int buf = 0;
  for (int ch = 0; ch < 8; ++ch) {
    __syncthreads();
    if (ch < 7) {
      gll16(ks0 + (size_t)(ch + 1) * 64 * NC, (char*)&Ks[buf ^ 1][0] + tid * 16);
      gll16(ks1 + (size_t)(ch + 1) * 64 * NC, (char*)&Ks[buf ^ 1][0] + (tid + 256) * 16);
      gll16(vs0 + (ch + 1) * 64, (char*)&Vs[buf ^ 1][0] + tid * 16);
      gll16(vs1 + (ch + 1) * 64, (char*)&Vs[buf ^ 1][0] + (tid + 256) * 16);
    }
    const char* kb = (const char*)&Ks[buf][0];
    const char* vb = (const char*)&Vs[buf][0];
#pragma unroll
    for (int half = 0; half < 2; ++half) {
      f32x16 st = {};
#pragma unroll
      for (int ks = 0; ks < 4; ++ks) {
        const int bo = ((2 * ks + h) ^ (c & 7)) * 16;
        const f16x8 kf = *(const f16x8*)(kb + (32 * half + c) * 128 + bo);
        st = MFMA32(kf, qf[ks], st);
      }
      u32 pk[8];
      float ps0 = 0.f, ps1 = 0.f;
#pragma unroll
      for (int t = 0; t < 8; ++t) {
        const float a0 = __builtin_amdgcn_exp2f(st[2 * t]);
        const float a1 = __builtin_amdgcn_exp2f(st[2 * t + 1]);
        ps0 += a0; ps1 += a1;
        pk[t] = pkf16(a0, a1);
      }
      l_run += ps0 + ps1;
#pragma unroll
      for (int ss = 0; ss < 2; ++ss) {
        const int s = half * 2 + ss, tb = ss * 4;
        const u32 xs = h ? pk[tb + 0] : pk[tb + 2];
        const u32 ys = h ? pk[tb + 1] : pk[tb + 3];
        const u32 rx = __shfl_xor(xs, 32);
        const u32 ry = __shfl_xor(ys, 32);
        u32x4 fi;
        fi[0] = h ? rx : pk[tb + 0];
        fi[1] = h ? ry : pk[tb + 1];
        fi[2] = h ? pk[tb + 2] : rx;
        fi[3] = h ? pk[tb + 3] : ry;
        const f16x8 pfrag = __builtin_bit_cast(f16x8, fi);
        const int bo = ((2 * s + h) ^ (c & 7)) * 16;
        const f16x8 v0 = *(const f16x8*)(vb + c * 128 + bo);
        const f16x8 v1 = *(const f16x8*)(vb + (32 + c) * 128 + bo);
        oa0 = MFMA32(v0, pfrag, oa0);
        oa1 = MFMA32(v1, pfrag, oa1);
      }
    }
    buf ^= 1;
  }
  const float ltot = l_run + __shfl_xor(l_run, 32);
  const float linv = 1.0f / ltot;
  f16* orow = O + qrow * NC + hh * 64;
#pragma unroll
  for (int dt = 0; dt < 2; ++dt) {
#pragma unroll
    for (int qd = 0; qd < 4; ++qd) {
      const float v0 = (dt ? oa1[4 * qd + 0] : oa0[4 * qd + 0]) * linv;
      const float v1 = (dt ? oa1[4 * qd + 1] : oa0[4 * qd + 1]) * linv;
      const float v2 = (dt ? oa1[4 * qd + 2] : oa0[4 * qd + 2]) * linv;
      const float v3 = (dt ? oa1[4 * qd + 3] : oa0[4 * qd + 3]) * linv;
      uint2 pr; pr.x = pkf16(v0, v1); pr.y = pkf16(v2, v3);
      *(uint2*)(orow + dt * 32 + 8 * qd + 4 * h) = pr;
    }
  }
}

// ---------------- launch ----------------
extern "C" void kernel_launch(void* const* d_in, const int* in_sizes, int n_in,
                              void* d_out, int out_size, void* d_ws, size_t ws_size,
                              hipStream_t stream) {
  const float* x   = (const float*)d_in[0];
  const float* cqw = (const float*)d_in[1];
  const float* ckw = (const float*)d_in[2];
  const float* cvw = (const float*)d_in[3];
  const float* bqg = (const float*)d_in[4],  *bqb = (const float*)d_in[5];
  const float* bqm = (const float*)d_in[6],  *bqv = (const float*)d_in[7];
  const float* bkg = (const float*)d_in[8],  *bkb = (const float*)d_in[9];
  const float* bkm = (const float*)d_in[10], *bkv = (const float*)d_in[11];
  const float* bvg = (const float*)d_in[12], *bvb = (const float*)d_in[13];
  const float* bvm = (const float*)d_in[14], *bvv = (const float*)d_in[15];
  const float* wq = (const float*)d_in[16];
  const float* wk = (const float*)d_in[17];
  const float* wv = (const float*)d_in[18];
  const float* pw = (const float*)d_in[19];
  const float* pb = (const float*)d_in[20];

  f16* q_tok = (f16*)d_out;                              // lo half (25 MB)
  f16* Qp    = (f16*)((char*)d_out + 25165824);          // hi half (25 MB)

  char* ws = (char*)d_ws;
  f16* wq_h  = (f16*)(ws + 0);
  f16* wk_h  = (f16*)(ws + 294912);
  f16* wv_h  = (f16*)(ws + 589824);
  f16* pw_h  = (f16*)(ws + 884736);
  f16* k_tok = (f16*)(ws + 1179648);
  f16* v_tok = (f16*)(ws + 4325376);
  f16* Kp    = (f16*)(ws + 7471104);
  f16* Vt    = (f16*)(ws + 10616832);
  f16* Oi    = (f16*)(ws + 13762560);
  float* wqT = (float*)(ws + 38928384);   // 41472 B each
  float* wkT = (float*)(ws + 38969856);
  float* wvT = (float*)(ws + 39011328);
  float* betq = (float*)(ws + 39052800);  // 1536 B each
  float* betk = (float*)(ws + 39054336);
  float* betv = (float*)(ws + 39055872);  // ws total 39,057,408 B

  const float scq = 0.051031036307982884f * 1.4426950408889634f; // 384^-0.5 * log2(e)
  cvt_w<<<dim3(576), dim3(256), 0, stream>>>(wq, wk, wv, pw, wq_h, wk_h, wv_h, pw_h,
                                             147456, scq);
  cvt_wt<<<dim3(27), dim3(384), 0, stream>>>(
      cqw, ckw, cvw,
      bqg, bqb, bqm, bqv, bkg, bkb, bkm, bkv, bvg, bvb, bvm, bvv,
      wqT, wkT, wvT, betq, betk, betv);
  conv_z1<<<dim3(192, 8, 16), dim3(128), 0, stream>>>(
      x, wqT, wkT, wvT, betq, betk, betv, q_tok, k_tok, v_tok);
  gemm_bt<0><<<dim3(3, 256), dim3(256), 0, stream>>>(q_tok, wq_h, Qp, nullptr);
  gemm_bt<0><<<dim3(3, 32),  dim3(256), 0, stream>>>(k_tok, wk_h, Kp, nullptr);
  gemm_bt<1><<<dim3(3, 32),  dim3(256), 0, stream>>>(v_tok, wv_h, Vt, nullptr);
  attn<<<dim3(32, 6, 8), dim3(256), 0, stream>>>(Qp, Kp, Vt, Oi);
  gemm_bt<2><<<dim3(3, 256), dim3(256), 0, stream>>>(Oi, pw_h, d_out, pb);
}

// Round 19
// 151.970 us; speedup vs baseline: 1.1022x; 1.1022x over previous
//
#include <hip/hip_runtime.h>
#include <hip/hip_bf16.h>
#include <stdint.h>

// Round 19: conv = the untried middle point: 128-thr blocks (R13 packing win)
// x z-chunk=4 (6144 blocks, ~2x R17 supply) x 3-slot ring (24 x-loads/z, half
// of R18). R14/R17/R18 showed duration pinned ~65us while occupancy/VALU
// scaled => limiter ~ per-CU VMEM throughput; this minimizes loads at high
// block supply. attn (R16) / GEMMs (R8) / prep (R17) frozen.

typedef _Float16 f16;
typedef _Float16 f16x8 __attribute__((ext_vector_type(8)));
typedef float f32x4 __attribute__((ext_vector_type(4)));
typedef float f32x16 __attribute__((ext_vector_type(16)));
typedef uint32_t u32;
typedef uint32_t u32x4 __attribute__((ext_vector_type(4)));

#define NC 384
#define MFMA16(A_,B_,C_) __builtin_amdgcn_mfma_f32_16x16x32_f16((A_),(B_),(C_),0,0,0)
#define MFMA32(A_,B_,C_) __builtin_amdgcn_mfma_f32_32x32x16_f16((A_),(B_),(C_),0,0,0)

__device__ __forceinline__ void gll16(const void* g, void* l) {
  __builtin_amdgcn_global_load_lds(
      (__attribute__((address_space(1))) void*)g,
      (__attribute__((address_space(3))) void*)l, 16, 0, 0);
}

__device__ __forceinline__ u32 pkf16(float lo, float hi) {
  return __builtin_bit_cast(u32, __builtin_amdgcn_cvt_pkrtz(lo, hi));
}

// ---------------- weight fp32 -> f16 convert (scq folded into wq) ----------------
__global__ __launch_bounds__(256) void cvt_w(
    const float* __restrict__ s0, const float* __restrict__ s1,
    const float* __restrict__ s2, const float* __restrict__ s3,
    f16* __restrict__ d0, f16* __restrict__ d1,
    f16* __restrict__ d2, f16* __restrict__ d3, int n, float scq)
{
  int i = blockIdx.x * 256 + threadIdx.x;
  if (i < n) {
    d0[i] = (f16)(s0[i] * scq);
    d1[i] = (f16)s1[i]; d2[i] = (f16)s2[i]; d3[i] = (f16)s3[i];
  }
}

// ---------------- conv-weight transpose + BN fold ----------------
__global__ __launch_bounds__(384) void cvt_wt(
    const float* __restrict__ wq, const float* __restrict__ wk, const float* __restrict__ wv,
    const float* __restrict__ bqg, const float* __restrict__ bqb,
    const float* __restrict__ bqm, const float* __restrict__ bqv,
    const float* __restrict__ bkg, const float* __restrict__ bkb,
    const float* __restrict__ bkm, const float* __restrict__ bkv,
    const float* __restrict__ bvg, const float* __restrict__ bvb,
    const float* __restrict__ bvm, const float* __restrict__ bvv,
    float* __restrict__ qT, float* __restrict__ kT, float* __restrict__ vT,
    float* __restrict__ betq, float* __restrict__ betk, float* __restrict__ betv)
{
  const int c = threadIdx.x;
  const int t = blockIdx.x;   // 0..26
  const float invq = bqg[c] * rsqrtf(bqv[c] + 1e-5f);
  const float invk = bkg[c] * rsqrtf(bkv[c] + 1e-5f);
  const float invv = bvg[c] * rsqrtf(bvv[c] + 1e-5f);
  qT[t * 384 + c] = wq[c * 27 + t] * invq;
  kT[t * 384 + c] = wk[c * 27 + t] * invk;
  vT[t * 384 + c] = wv[c * 27 + t] * invv;
  if (t == 0) {
    betq[c] = bqb[c] - bqm[c] * invq;
    betk[c] = bkb[c] - bkm[c] * invk;
    betv[c] = bvb[c] - bvm[c] * invv;
  }
}

// ---------------- fused depthwise conv3d + BN, z-chunk=4, 3-slot ring ----------------
// 128 thr (2 waves); grid (64 tiles x 3 c-thirds, 8 b, 4 z-chunks).
__global__ __launch_bounds__(128) void conv_fused(
    const float* __restrict__ x,
    const float* __restrict__ wqT, const float* __restrict__ wkT, const float* __restrict__ wvT,
    const float* __restrict__ betq_, const float* __restrict__ betk_,
    const float* __restrict__ betv_,
    f16* __restrict__ qout, f16* __restrict__ kout, f16* __restrict__ vout)
{
  const int tile = blockIdx.x / 3, cthird = blockIdx.x % 3;
  const int c = cthird * 128 + threadIdx.x;
  const int th = tile >> 3, tw = tile & 7;
  const int b = blockIdx.y;
  const int z0 = blockIdx.z * 4;
  const int h0 = th * 2, w0 = tw * 2;

  float wqr[27], wkr[27], wvr[27];
#pragma unroll
  for (int t = 0; t < 27; ++t) {
    wqr[t] = wqT[t * 384 + c];   // pre-scaled by BN inv
    wkr[t] = wkT[t * 384 + c];
    wvr[t] = wvT[t * 384 + c];
  }
  const float betq = betq_[c], betk = betk_[c], betv = betv_[c];

  bool hok[4], wok[4];
#pragma unroll
  for (int a = 0; a < 4; ++a) {
    hok[a] = (unsigned)(h0 - 1 + a) < 16u;
    wok[a] = (unsigned)(w0 - 1 + a) < 16u;
  }
  const float* xb = x + (size_t)b * 4096 * NC + c;

  float win[3][4][4];   // plane t = z0-1+t -> slot t%3
  auto ldplane = [&](int s, int iz) {   // s compile-time after unroll
    const bool zok = (unsigned)iz < 16u;
#pragma unroll
    for (int a = 0; a < 4; ++a)
#pragma unroll
      for (int e = 0; e < 4; ++e) {
        float v = 0.f;
        if (zok && hok[a] && wok[e])
          v = xb[(size_t)((h0 - 1 + a) * 256 + (w0 - 1 + e) * 16 + iz) * NC];
        win[s][a][e] = v;
      }
  };
  ldplane(0, z0 - 1);
  ldplane(1, z0);

#pragma unroll
  for (int zr = 0; zr < 4; ++zr) {
    const int z = z0 + zr;
    ldplane((zr + 2) % 3, z + 1);   // plane t = zr+2
    float aq00 = 0.f, aq01 = 0.f, aq10 = 0.f, aq11 = 0.f;
    float ak = 0.f, av = 0.f;
#pragma unroll
    for (int p = 0; p < 3; ++p) {
      const int s = (zr + p) % 3;   // planes z-1..z+1
#pragma unroll
      for (int a = 0; a < 3; ++a)
#pragma unroll
        for (int e = 0; e < 3; ++e) {
          const float w00 = win[s][a][e],     w01 = win[s][a][e + 1];
          const float w10 = win[s][a + 1][e], w11 = win[s][a + 1][e + 1];
          const float cq = wqr[a * 9 + e * 3 + p];
          aq00 += w00 * cq; aq01 += w01 * cq;
          aq10 += w10 * cq; aq11 += w11 * cq;
          if ((zr & 1) == 0) {               // z0 mult of 4 -> z even iff zr even
            ak += w00 * wkr[a * 9 + e * 3 + p];
            av += w00 * wvr[a * 9 + e * 3 + p];
          }
        }
    }
    const size_t qb = (size_t)b * 4096;
    qout[(qb + (h0 + 0) * 256 + (w0 + 0) * 16 + z) * NC + c] = (f16)(aq00 + betq);
    qout[(qb + (h0 + 0) * 256 + (w0 + 1) * 16 + z) * NC + c] = (f16)(aq01 + betq);
    qout[(qb + (h0 + 1) * 256 + (w0 + 0) * 16 + z) * NC + c] = (f16)(aq10 + betq);
    qout[(qb + (h0 + 1) * 256 + (w0 + 1) * 16 + z) * NC + c] = (f16)(aq11 + betq);
    if ((zr & 1) == 0) {
      const size_t t = (size_t)b * 512 + tile * 8 + (z >> 1);
      kout[t * NC + c] = (f16)(ak + betk);
      vout[t * NC + c] = (f16)(av + betv);
    }
  }
}

// ---------------- GEMM (R8 version): gll16 staging + XOR-swizzled LDS ----------------
template<int MODE>
__global__ __launch_bounds__(256) void gemm_bt(
    const f16* __restrict__ A, const f16* __restrict__ Bw,
    void* __restrict__ Cout, const float* __restrict__ bias)
{
  __shared__ f16 As[128 * 64];
  __shared__ f16 Bs[128 * 64];
  const int tid = threadIdx.x;
  const int w = tid >> 6, lane = tid & 63;
  const int g = lane >> 4, q = lane & 15;
  const int wr = w >> 1, wc = w & 1;
  const size_t brow = (size_t)blockIdx.y * 128;
  const int bcol = blockIdx.x * 128;
  const int srow = lane >> 3;
  const int sbb  = (lane & 7) ^ (srow & 7);
  f32x4 acc[4][4] = {};
  for (int kt = 0; kt < 6; ++kt) {
    const int k0 = kt * 64;
#pragma unroll
    for (int j = 0; j < 4; ++j) {
      const int s = w * 4 + j;
      gll16(A  + (brow + (size_t)(s * 8 + srow)) * NC + k0 + sbb * 8, (char*)As + s * 1024);
      gll16(Bw + (size_t)(bcol + s * 8 + srow) * NC + k0 + sbb * 8, (char*)Bs + s * 1024);
    }
    __syncthreads();
#pragma unroll
    for (int ks = 0; ks < 2; ++ks) {
      f16x8 af[4], bfr[4];
      const int bb = ((g + 4 * ks) ^ (q & 7)) * 16;
#pragma unroll
      for (int m = 0; m < 4; ++m) {
        af[m]  = *(const f16x8*)((const char*)As + (wr * 64 + m * 16 + q) * 128 + bb);
        bfr[m] = *(const f16x8*)((const char*)Bs + (wc * 64 + m * 16 + q) * 128 + bb);
      }
#pragma unroll
      for (int m = 0; m < 4; ++m)
#pragma unroll
        for (int n = 0; n < 4; ++n)
          acc[m][n] = MFMA16(af[m], bfr[n], acc[m][n]);
    }
    __syncthreads();
  }
  float bvals[4];
  if (MODE == 2) {
#pragma unroll
    for (int n = 0; n < 4; ++n) bvals[n] = bias[bcol + wc * 64 + n * 16 + q];
  }
#pragma unroll
  for (int m = 0; m < 4; ++m) {
#pragma unroll
    for (int n = 0; n < 4; ++n) {
#pragma unroll
      for (int r = 0; r < 4; ++r) {
        const size_t row = brow + wr * 64 + m * 16 + 4 * g + r;
        const int col = bcol + wc * 64 + n * 16 + q;
        const float v = acc[m][n][r];
        if (MODE == 0) {
          ((f16*)Cout)[row * NC + col] = (f16)v;
        } else if (MODE == 1) {
          const size_t bi = row >> 9, t = row & 511;
          ((f16*)Cout)[(bi * NC + col) * 512 + t] = (f16)v;
        } else {
          ((float*)Cout)[row * NC + col] = v + bvals[n];
        }
      }
    }
  }
}

// ---------------- flash attention (R16): per-half pipeline, v_exp_f32 ----------------
__global__ __launch_bounds__(256) void attn(
    const f16* __restrict__ Qp, const f16* __restrict__ Kp,
    const f16* __restrict__ Vt, f16* __restrict__ O)
{
  __shared__ f16 Ks[2][64 * 64];
  __shared__ f16 Vs[2][64 * 64];
  const int tid = threadIdx.x;
  const int w = tid >> 6, lane = tid & 63;
  const int c = lane & 31, h = lane >> 5;
  const int qt = blockIdx.x, hh = blockIdx.y, b = blockIdx.z;
  const size_t qrow = (size_t)b * 4096 + qt * 128 + w * 32 + c;

  f16x8 qf[4];
#pragma unroll
  for (int ks = 0; ks < 4; ++ks)
    qf[ks] = *(const f16x8*)(Qp + qrow * NC + hh * 64 + ks * 16 + 8 * h);

  f32x16 oa0 = {}, oa1 = {};
  float l_run = 0.f;

  const int r0 = tid >> 3, k0b = tid & 7;
  const int r1 = (tid + 256) >> 3, k1b = tid & 7;
  const f16* ks0 = Kp + ((size_t)b * 512 + r0) * NC + hh * 64 + ((k0b ^ (r0 & 7)) * 8);
  const f16* ks1 = Kp + ((size_t)b * 512 + r1) * NC + hh * 64 + ((k1b ^ (r1 & 7)) * 8);
  const f16* vs0 = Vt + ((size_t)b * NC + hh * 64 + r0) * 512 + ((k0b ^ (r0 & 7)) * 8);
  const f16* vs1 = Vt + ((size_t)b * NC + hh * 64 + r1) * 512 + ((k1b ^ (r1 & 7)) * 8);
  gll16(ks0, (char*)&Ks[0][0] + tid * 16);
  gll16(ks1, (char*)&Ks[0][0] + (tid + 256) * 16);
  gll16(vs0, (char*)&Vs[0][0] + tid * 16);
  gll16(vs1, (char*)&Vs[0][0] + (tid + 256) * 16);

  int buf = 0;
  for (int ch = 0; ch < 8; ++ch) {
    __syncthreads();
    if (ch < 7) {
      gll16(ks0 + (size_t)(ch + 1) * 64 * NC, (char*)&Ks[buf ^ 1][0] + tid * 16);
      gll16(ks1 + (size_t)(ch + 1) * 64 * NC, (char*)&Ks[buf ^ 1][0] + (tid + 256) * 16);
      gll16(vs0 + (ch + 1) * 64, (char*)&Vs[buf ^ 1][0] + tid * 16);
      gll16(vs1 + (ch + 1) * 64, (char*)&Vs[buf ^ 1][0] + (tid + 256) * 16);
    }
    const char* kb = (const char*)&Ks[buf][0];
    const char* vb = (const char*)&Vs[buf][0];
#pragma unroll
    for (int half = 0; half < 2; ++half) {
      f32x16 st = {};
#pragma unroll
      for (int ks = 0; ks < 4; ++ks) {
        const int bo = ((2 * ks + h) ^ (c & 7)) * 16;
        const f16x8 kf = *(const f16x8*)(kb + (32 * half + c) * 128 + bo);
        st = MFMA32(kf, qf[ks], st);
      }
      u32 pk[8];
      float ps0 = 0.f, ps1 = 0.f;
#pragma unroll
      for (int t = 0; t < 8; ++t) {
        const float a0 = __builtin_amdgcn_exp2f(st[2 * t]);
        const float a1 = __builtin_amdgcn_exp2f(st[2 * t + 1]);
        ps0 += a0; ps1 += a1;
        pk[t] = pkf16(a0, a1);
      }
      l_run += ps0 + ps1;
#pragma unroll
      for (int ss = 0; ss < 2; ++ss) {
        const int s = half * 2 + ss, tb = ss * 4;
        const u32 xs = h ? pk[tb + 0] : pk[tb + 2];
        const u32 ys = h ? pk[tb + 1] : pk[tb + 3];
        const u32 rx = __shfl_xor(xs, 32);
        const u32 ry = __shfl_xor(ys, 32);
        u32x4 fi;
        fi[0] = h ? rx : pk[tb + 0];
        fi[1] = h ? ry : pk[tb + 1];
        fi[2] = h ? pk[tb + 2] : rx;
        fi[3] = h ? pk[tb + 3] : ry;
        const f16x8 pfrag = __builtin_bit_cast(f16x8, fi);
        const int bo = ((2 * s + h) ^ (c & 7)) * 16;
        const f16x8 v0 = *(const f16x8*)(vb + c * 128 + bo);
        const f16x8 v1 = *(const f16x8*)(vb + (32 + c) * 128 + bo);
        oa0 = MFMA32(v0, pfrag, oa0);
        oa1 = MFMA32(v1, pfrag, oa1);
      }
    }
    buf ^= 1;
  }
  const float ltot = l_run + __shfl_xor(l_run, 32);
  const float linv = 1.0f / ltot;
  f16* orow = O + qrow * NC + hh * 64;
#pragma unroll
  for (int dt = 0; dt < 2; ++dt) {
#pragma unroll
    for (int qd = 0; qd < 4; ++qd) {
      const float v0 = (dt ? oa1[4 * qd + 0] : oa0[4 * qd + 0]) * linv;
      const float v1 = (dt ? oa1[4 * qd + 1] : oa0[4 * qd + 1]) * linv;
      const float v2 = (dt ? oa1[4 * qd + 2] : oa0[4 * qd + 2]) * linv;
      const float v3 = (dt ? oa1[4 * qd + 3] : oa0[4 * qd + 3]) * linv;
      uint2 pr; pr.x = pkf16(v0, v1); pr.y = pkf16(v2, v3);
      *(uint2*)(orow + dt * 32 + 8 * qd + 4 * h) = pr;
    }
  }
}

// ---------------- launch ----------------
extern "C" void kernel_launch(void* const* d_in, const int* in_sizes, int n_in,
                              void* d_out, int out_size, void* d_ws, size_t ws_size,
                              hipStream_t stream) {
  const float* x   = (const float*)d_in[0];
  const float* cqw = (const float*)d_in[1];
  const float* ckw = (const float*)d_in[2];
  const float* cvw = (const float*)d_in[3];
  const float* bqg = (const float*)d_in[4],  *bqb = (const float*)d_in[5];
  const float* bqm = (const float*)d_in[6],  *bqv = (const float*)d_in[7];
  const float* bkg = (const float*)d_in[8],  *bkb = (const float*)d_in[9];
  const float* bkm = (const float*)d_in[10], *bkv = (const float*)d_in[11];
  const float* bvg = (const float*)d_in[12], *bvb = (const float*)d_in[13];
  const float* bvm = (const float*)d_in[14], *bvv = (const float*)d_in[15];
  const float* wq = (const float*)d_in[16];
  const float* wk = (const float*)d_in[17];
  const float* wv = (const float*)d_in[18];
  const float* pw = (const float*)d_in[19];
  const float* pb = (const float*)d_in[20];

  f16* q_tok = (f16*)d_out;                              // lo half (25 MB)
  f16* Qp    = (f16*)((char*)d_out + 25165824);          // hi half (25 MB)

  char* ws = (char*)d_ws;
  f16* wq_h  = (f16*)(ws + 0);
  f16* wk_h  = (f16*)(ws + 294912);
  f16* wv_h  = (f16*)(ws + 589824);
  f16* pw_h  = (f16*)(ws + 884736);
  f16* k_tok = (f16*)(ws + 1179648);
  f16* v_tok = (f16*)(ws + 4325376);
  f16* Kp    = (f16*)(ws + 7471104);
  f16* Vt    = (f16*)(ws + 10616832);
  f16* Oi    = (f16*)(ws + 13762560);
  float* wqT = (float*)(ws + 38928384);
  float* wkT = (float*)(ws + 38969856);
  float* wvT = (float*)(ws + 39011328);
  float* betq = (float*)(ws + 39052800);
  float* betk = (float*)(ws + 39054336);
  float* betv = (float*)(ws + 39055872);  // ws total 39,057,408 B

  const float scq = 0.051031036307982884f * 1.4426950408889634f; // 384^-0.5 * log2(e)
  cvt_w<<<dim3(576), dim3(256), 0, stream>>>(wq, wk, wv, pw, wq_h, wk_h, wv_h, pw_h,
                                             147456, scq);
  cvt_wt<<<dim3(27), dim3(384), 0, stream>>>(
      cqw, ckw, cvw,
      bqg, bqb, bqm, bqv, bkg, bkb, bkm, bkv, bvg, bvb, bvm, bvv,
      wqT, wkT, wvT, betq, betk, betv);
  conv_fused<<<dim3(192, 8, 4), dim3(128), 0, stream>>>(
      x, wqT, wkT, wvT, betq, betk, betv, q_tok, k_tok, v_tok);
  gemm_bt<0><<<dim3(3, 256), dim3(256), 0, stream>>>(q_tok, wq_h, Qp, nullptr);
  gemm_bt<0><<<dim3(3, 32),  dim3(256), 0, stream>>>(k_tok, wk_h, Kp, nullptr);
  gemm_bt<1><<<dim3(3, 32),  dim3(256), 0, stream>>>(v_tok, wv_h, Vt, nullptr);
  attn<<<dim3(32, 6, 8), dim3(256), 0, stream>>>(Qp, Kp, Vt, Oi);
  gemm_bt<2><<<dim3(3, 256), dim3(256), 0, stream>>>(Oi, pw_h, d_out, pb);
}

// Round 20
// 141.112 us; speedup vs baseline: 1.1870x; 1.0770x over previous
//
#include <hip/hip_runtime.h>
#include <hip/hip_bf16.h>
#include <stdint.h>

// Round 20: fuse Q-projection into attn (phase-1 mini-GEMM -> Qtmp LDS ->
// qf frags). Removes gemmQ dispatch + 50 MB Qp round-trip. conv = R19 (58us,
// parked). K/V gemms, out-gemm, prep frozen.

typedef _Float16 f16;
typedef _Float16 f16x8 __attribute__((ext_vector_type(8)));
typedef float f32x4 __attribute__((ext_vector_type(4)));
typedef float f32x16 __attribute__((ext_vector_type(16)));
typedef uint32_t u32;
typedef uint32_t u32x4 __attribute__((ext_vector_type(4)));

#define NC 384
#define MFMA16(A_,B_,C_) __builtin_amdgcn_mfma_f32_16x16x32_f16((A_),(B_),(C_),0,0,0)
#define MFMA32(A_,B_,C_) __builtin_amdgcn_mfma_f32_32x32x16_f16((A_),(B_),(C_),0,0,0)

__device__ __forceinline__ void gll16(const void* g, void* l) {
  __builtin_amdgcn_global_load_lds(
      (__attribute__((address_space(1))) void*)g,
      (__attribute__((address_space(3))) void*)l, 16, 0, 0);
}

__device__ __forceinline__ u32 pkf16(float lo, float hi) {
  return __builtin_bit_cast(u32, __builtin_amdgcn_cvt_pkrtz(lo, hi));
}

// ---------------- weight fp32 -> f16 convert (scq folded into wq) ----------------
__global__ __launch_bounds__(256) void cvt_w(
    const float* __restrict__ s0, const float* __restrict__ s1,
    const float* __restrict__ s2, const float* __restrict__ s3,
    f16* __restrict__ d0, f16* __restrict__ d1,
    f16* __restrict__ d2, f16* __restrict__ d3, int n, float scq)
{
  int i = blockIdx.x * 256 + threadIdx.x;
  if (i < n) {
    d0[i] = (f16)(s0[i] * scq);
    d1[i] = (f16)s1[i]; d2[i] = (f16)s2[i]; d3[i] = (f16)s3[i];
  }
}

// ---------------- conv-weight transpose + BN fold ----------------
__global__ __launch_bounds__(384) void cvt_wt(
    const float* __restrict__ wq, const float* __restrict__ wk, const float* __restrict__ wv,
    const float* __restrict__ bqg, const float* __restrict__ bqb,
    const float* __restrict__ bqm, const float* __restrict__ bqv,
    const float* __restrict__ bkg, const float* __restrict__ bkb,
    const float* __restrict__ bkm, const float* __restrict__ bkv,
    const float* __restrict__ bvg, const float* __restrict__ bvb,
    const float* __restrict__ bvm, const float* __restrict__ bvv,
    float* __restrict__ qT, float* __restrict__ kT, float* __restrict__ vT,
    float* __restrict__ betq, float* __restrict__ betk, float* __restrict__ betv)
{
  const int c = threadIdx.x;
  const int t = blockIdx.x;   // 0..26
  const float invq = bqg[c] * rsqrtf(bqv[c] + 1e-5f);
  const float invk = bkg[c] * rsqrtf(bkv[c] + 1e-5f);
  const float invv = bvg[c] * rsqrtf(bvv[c] + 1e-5f);
  qT[t * 384 + c] = wq[c * 27 + t] * invq;
  kT[t * 384 + c] = wk[c * 27 + t] * invk;
  vT[t * 384 + c] = wv[c * 27 + t] * invv;
  if (t == 0) {
    betq[c] = bqb[c] - bqm[c] * invq;
    betk[c] = bkb[c] - bkm[c] * invk;
    betv[c] = bvb[c] - bvm[c] * invv;
  }
}

// ---------------- fused depthwise conv3d + BN (R19), z-chunk=4, 3-slot ring ----------------
__global__ __launch_bounds__(128) void conv_fused(
    const float* __restrict__ x,
    const float* __restrict__ wqT, const float* __restrict__ wkT, const float* __restrict__ wvT,
    const float* __restrict__ betq_, const float* __restrict__ betk_,
    const float* __restrict__ betv_,
    f16* __restrict__ qout, f16* __restrict__ kout, f16* __restrict__ vout)
{
  const int tile = blockIdx.x / 3, cthird = blockIdx.x % 3;
  const int c = cthird * 128 + threadIdx.x;
  const int th = tile >> 3, tw = tile & 7;
  const int b = blockIdx.y;
  const int z0 = blockIdx.z * 4;
  const int h0 = th * 2, w0 = tw * 2;

  float wqr[27], wkr[27], wvr[27];
#pragma unroll
  for (int t = 0; t < 27; ++t) {
    wqr[t] = wqT[t * 384 + c];
    wkr[t] = wkT[t * 384 + c];
    wvr[t] = wvT[t * 384 + c];
  }
  const float betq = betq_[c], betk = betk_[c], betv = betv_[c];

  bool hok[4], wok[4];
#pragma unroll
  for (int a = 0; a < 4; ++a) {
    hok[a] = (unsigned)(h0 - 1 + a) < 16u;
    wok[a] = (unsigned)(w0 - 1 + a) < 16u;
  }
  const float* xb = x + (size_t)b * 4096 * NC + c;

  float win[3][4][4];
  auto ldplane = [&](int s, int iz) {
    const bool zok = (unsigned)iz < 16u;
#pragma unroll
    for (int a = 0; a < 4; ++a)
#pragma unroll
      for (int e = 0; e < 4; ++e) {
        float v = 0.f;
        if (zok && hok[a] && wok[e])
          v = xb[(size_t)((h0 - 1 + a) * 256 + (w0 - 1 + e) * 16 + iz) * NC];
        win[s][a][e] = v;
      }
  };
  ldplane(0, z0 - 1);
  ldplane(1, z0);

#pragma unroll
  for (int zr = 0; zr < 4; ++zr) {
    const int z = z0 + zr;
    ldplane((zr + 2) % 3, z + 1);
    float aq00 = 0.f, aq01 = 0.f, aq10 = 0.f, aq11 = 0.f;
    float ak = 0.f, av = 0.f;
#pragma unroll
    for (int p = 0; p < 3; ++p) {
      const int s = (zr + p) % 3;
#pragma unroll
      for (int a = 0; a < 3; ++a)
#pragma unroll
        for (int e = 0; e < 3; ++e) {
          const float w00 = win[s][a][e],     w01 = win[s][a][e + 1];
          const float w10 = win[s][a + 1][e], w11 = win[s][a + 1][e + 1];
          const float cq = wqr[a * 9 + e * 3 + p];
          aq00 += w00 * cq; aq01 += w01 * cq;
          aq10 += w10 * cq; aq11 += w11 * cq;
          if ((zr & 1) == 0) {
            ak += w00 * wkr[a * 9 + e * 3 + p];
            av += w00 * wvr[a * 9 + e * 3 + p];
          }
        }
    }
    const size_t qb = (size_t)b * 4096;
    qout[(qb + (h0 + 0) * 256 + (w0 + 0) * 16 + z) * NC + c] = (f16)(aq00 + betq);
    qout[(qb + (h0 + 0) * 256 + (w0 + 1) * 16 + z) * NC + c] = (f16)(aq01 + betq);
    qout[(qb + (h0 + 1) * 256 + (w0 + 0) * 16 + z) * NC + c] = (f16)(aq10 + betq);
    qout[(qb + (h0 + 1) * 256 + (w0 + 1) * 16 + z) * NC + c] = (f16)(aq11 + betq);
    if ((zr & 1) == 0) {
      const size_t t = (size_t)b * 512 + tile * 8 + (z >> 1);
      kout[t * NC + c] = (f16)(ak + betk);
      vout[t * NC + c] = (f16)(av + betv);
    }
  }
}

// ---------------- GEMM (R8 version): gll16 staging + XOR-swizzled LDS ----------------
template<int MODE>
__global__ __launch_bounds__(256) void gemm_bt(
    const f16* __restrict__ A, const f16* __restrict__ Bw,
    void* __restrict__ Cout, const float* __restrict__ bias)
{
  __shared__ f16 As[128 * 64];
  __shared__ f16 Bs[128 * 64];
  const int tid = threadIdx.x;
  const int w = tid >> 6, lane = tid & 63;
  const int g = lane >> 4, q = lane & 15;
  const int wr = w >> 1, wc = w & 1;
  const size_t brow = (size_t)blockIdx.y * 128;
  const int bcol = blockIdx.x * 128;
  const int srow = lane >> 3;
  const int sbb  = (lane & 7) ^ (srow & 7);
  f32x4 acc[4][4] = {};
  for (int kt = 0; kt < 6; ++kt) {
    const int k0 = kt * 64;
#pragma unroll
    for (int j = 0; j < 4; ++j) {
      const int s = w * 4 + j;
      gll16(A  + (brow + (size_t)(s * 8 + srow)) * NC + k0 + sbb * 8, (char*)As + s * 1024);
      gll16(Bw + (size_t)(bcol + s * 8 + srow) * NC + k0 + sbb * 8, (char*)Bs + s * 1024);
    }
    __syncthreads();
#pragma unroll
    for (int ks = 0; ks < 2; ++ks) {
      f16x8 af[4], bfr[4];
      const int bb = ((g + 4 * ks) ^ (q & 7)) * 16;
#pragma unroll
      for (int m = 0; m < 4; ++m) {
        af[m]  = *(const f16x8*)((const char*)As + (wr * 64 + m * 16 + q) * 128 + bb);
        bfr[m] = *(const f16x8*)((const char*)Bs + (wc * 64 + m * 16 + q) * 128 + bb);
      }
#pragma unroll
      for (int m = 0; m < 4; ++m)
#pragma unroll
        for (int n = 0; n < 4; ++n)
          acc[m][n] = MFMA16(af[m], bfr[n], acc[m][n]);
    }
    __syncthreads();
  }
  float bvals[4];
  if (MODE == 2) {
#pragma unroll
    for (int n = 0; n < 4; ++n) bvals[n] = bias[bcol + wc * 64 + n * 16 + q];
  }
#pragma unroll
  for (int m = 0; m < 4; ++m) {
#pragma unroll
    for (int n = 0; n < 4; ++n) {
#pragma unroll
      for (int r = 0; r < 4; ++r) {
        const size_t row = brow + wr * 64 + m * 16 + 4 * g + r;
        const int col = bcol + wc * 64 + n * 16 + q;
        const float v = acc[m][n][r];
        if (MODE == 0) {
          ((f16*)Cout)[row * NC + col] = (f16)v;
        } else if (MODE == 1) {
          const size_t bi = row >> 9, t = row & 511;
          ((f16*)Cout)[(bi * NC + col) * 512 + t] = (f16)v;
        } else {
          ((float*)Cout)[row * NC + col] = v + bvals[n];
        }
      }
    }
  }
}

// ---------------- flash attention with fused Q-projection ----------------
// grid (32 qtiles, 6 heads, 8 b); 256 thr = 4 waves x 32 q-rows.
// Phase 1: Q[128x64] = q_tok[128x384] . Wq_head^T via MFMA32 (C = [d][qrow]),
// repacked through padded Qtmp into qf B-frags. Phase 2: R16 loop unchanged.
__global__ __launch_bounds__(256) void attn(
    const f16* __restrict__ qtok, const f16* __restrict__ wqh,
    const f16* __restrict__ Kp, const f16* __restrict__ Vt, f16* __restrict__ O)
{
  __shared__ f16 Ks[2][64 * 64];   // phase1: q_tok tile staging (16 KB)
  __shared__ f16 Vs[2][64 * 64];   // Vs[1] = phase1 wq staging
  __shared__ f16 Qtmp[128 * 72];   // padded Q tile (18 KB)
  const int tid = threadIdx.x;
  const int w = tid >> 6, lane = tid & 63;
  const int c = lane & 31, h = lane >> 5;
  const int qt = blockIdx.x, hh = blockIdx.y, b = blockIdx.z;
  const size_t qrow0b = (size_t)b * 4096 + qt * 128;
  const size_t qrow = qrow0b + w * 32 + c;

  // staging addresses (phase 2)
  const int r0 = tid >> 3, k0b = tid & 7;
  const int r1 = (tid + 256) >> 3;
  const f16* ks0 = Kp + ((size_t)b * 512 + r0) * NC + hh * 64 + ((k0b ^ (r0 & 7)) * 8);
  const f16* ks1 = Kp + ((size_t)b * 512 + r1) * NC + hh * 64 + ((k0b ^ (r1 & 7)) * 8);
  const f16* vs0 = Vt + ((size_t)b * NC + hh * 64 + r0) * 512 + ((k0b ^ (r0 & 7)) * 8);
  const f16* vs1 = Vt + ((size_t)b * NC + hh * 64 + r1) * 512 + ((k0b ^ (r1 & 7)) * 8);
  // V chunk 0 prefetch now (Vs[0] untouched by phase 1)
  gll16(vs0, (char*)&Vs[0][0] + tid * 16);
  gll16(vs1, (char*)&Vs[0][0] + (tid + 256) * 16);

  // ---- Phase 1: Q-projection ----
  {
    char* QsFlat = (char*)&Ks[0][0];   // 16 KB
    char* WqFlat = (char*)&Vs[1][0];   // 8 KB
    const int srow = lane >> 3, sbb = (lane & 7) ^ (srow & 7);
    f32x16 qa0 = {}, qa1 = {};
    for (int kt = 0; kt < 6; ++kt) {
#pragma unroll
      for (int j = 0; j < 4; ++j) {
        const int s = w * 4 + j;
        gll16(qtok + (qrow0b + (size_t)(s * 8 + srow)) * NC + kt * 64 + sbb * 8,
              QsFlat + s * 1024);
      }
#pragma unroll
      for (int j = 0; j < 2; ++j) {
        const int i = tid + j * 256;
        const int row = i >> 3, blk = i & 7;
        gll16(wqh + (size_t)(hh * 64 + row) * NC + kt * 64 + ((blk ^ (row & 7)) * 8),
              WqFlat + i * 16);
      }
      __syncthreads();
#pragma unroll
      for (int ks = 0; ks < 4; ++ks) {
        const int bo = ((2 * ks + h) ^ (c & 7)) * 16;
        const f16x8 bq = *(const f16x8*)(QsFlat + (w * 32 + c) * 128 + bo);
        const f16x8 a0 = *(const f16x8*)(WqFlat + c * 128 + bo);
        const f16x8 a1 = *(const f16x8*)(WqFlat + (32 + c) * 128 + bo);
        qa0 = MFMA32(a0, bq, qa0);
        qa1 = MFMA32(a1, bq, qa1);
      }
      __syncthreads();
    }
    // write Q tile: lane (c,h) holds Q[d = t*32 + 8*g4 + 4h + j][qrow = w*32+c]
#pragma unroll
    for (int t = 0; t < 2; ++t) {
#pragma unroll
      for (int g4 = 0; g4 < 4; ++g4) {
        const float q0 = t ? qa1[4 * g4 + 0] : qa0[4 * g4 + 0];
        const float q1 = t ? qa1[4 * g4 + 1] : qa0[4 * g4 + 1];
        const float q2 = t ? qa1[4 * g4 + 2] : qa0[4 * g4 + 2];
        const float q3 = t ? qa1[4 * g4 + 3] : qa0[4 * g4 + 3];
        uint2 pr; pr.x = pkf16(q0, q1); pr.y = pkf16(q2, q3);
        *(uint2*)((char*)Qtmp + ((w * 32 + c) * 72 + t * 32 + 8 * g4 + 4 * h) * 2) = pr;
      }
    }
    __syncthreads();
  }
  f16x8 qf[4];
#pragma unroll
  for (int ks = 0; ks < 4; ++ks)
    qf[ks] = *(const f16x8*)((const char*)Qtmp + ((w * 32 + c) * 72 + ks * 16 + 8 * h) * 2);
  // K chunk 0 prefetch (Ks free now)
  gll16(ks0, (char*)&Ks[0][0] + tid * 16);
  gll16(ks1, (char*)&Ks[0][0] + (tid + 256) * 16);

  // ---- Phase 2: R16 main loop ----
  f32x16 oa0 = {}, oa1 = {};
  float l_run = 0.f;
  int buf = 0;
  for (int ch = 0; ch < 8; ++ch) {
    __syncthreads();
    if (ch < 7) {
      gll16(ks0 + (size_t)(ch + 1) * 64 * NC, (char*)&Ks[buf ^ 1][0] + tid * 16);
      gll16(ks1 + (size_t)(ch + 1) * 64 * NC, (char*)&Ks[buf ^ 1][0] + (tid + 256) * 16);
      gll16(vs0 + (ch + 1) * 64, (char*)&Vs[buf ^ 1][0] + tid * 16);
      gll16(vs1 + (ch + 1) * 64, (char*)&Vs[buf ^ 1][0] + (tid + 256) * 16);
    }
    const char* kb = (const char*)&Ks[buf][0];
    const char* vb = (const char*)&Vs[buf][0];
#pragma unroll
    for (int half = 0; half < 2; ++half) {
      f32x16 st = {};
#pragma unroll
      for (int ks = 0; ks < 4; ++ks) {
        const int bo = ((2 * ks + h) ^ (c & 7)) * 16;
        const f16x8 kf = *(const f16x8*)(kb + (32 * half + c) * 128 + bo);
        st = MFMA32(kf, qf[ks], st);
      }
      u32 pk[8];
      float ps0 = 0.f, ps1 = 0.f;
#pragma unroll
      for (int t = 0; t < 8; ++t) {
        const float a0 = __builtin_amdgcn_exp2f(st[2 * t]);
        const float a1 = __builtin_amdgcn_exp2f(st[2 * t + 1]);
        ps0 += a0; ps1 += a1;
        pk[t] = pkf16(a0, a1);
      }
      l_run += ps0 + ps1;
#pragma unroll
      for (int ss = 0; ss < 2; ++ss) {
        const int s = half * 2 + ss, tb = ss * 4;
        const u32 xs = h ? pk[tb + 0] : pk[tb + 2];
        const u32 ys = h ? pk[tb + 1] : pk[tb + 3];
        const u32 rx = __shfl_xor(xs, 32);
        const u32 ry = __shfl_xor(ys, 32);
        u32x4 fi;
        fi[0] = h ? rx : pk[tb + 0];
        fi[1] = h ? ry : pk[tb + 1];
        fi[2] = h ? pk[tb + 2] : rx;
        fi[3] = h ? pk[tb + 3] : ry;
        const f16x8 pfrag = __builtin_bit_cast(f16x8, fi);
        const int bo = ((2 * s + h) ^ (c & 7)) * 16;
        const f16x8 v0 = *(const f16x8*)(vb + c * 128 + bo);
        const f16x8 v1 = *(const f16x8*)(vb + (32 + c) * 128 + bo);
        oa0 = MFMA32(v0, pfrag, oa0);
        oa1 = MFMA32(v1, pfrag, oa1);
      }
    }
    buf ^= 1;
  }
  const float ltot = l_run + __shfl_xor(l_run, 32);
  const float linv = 1.0f / ltot;
  f16* orow = O + qrow * NC + hh * 64;
#pragma unroll
  for (int dt = 0; dt < 2; ++dt) {
#pragma unroll
    for (int qd = 0; qd < 4; ++qd) {
      const float v0 = (dt ? oa1[4 * qd + 0] : oa0[4 * qd + 0]) * linv;
      const float v1 = (dt ? oa1[4 * qd + 1] : oa0[4 * qd + 1]) * linv;
      const float v2 = (dt ? oa1[4 * qd + 2] : oa0[4 * qd + 2]) * linv;
      const float v3 = (dt ? oa1[4 * qd + 3] : oa0[4 * qd + 3]) * linv;
      uint2 pr; pr.x = pkf16(v0, v1); pr.y = pkf16(v2, v3);
      *(uint2*)(orow + dt * 32 + 8 * qd + 4 * h) = pr;
    }
  }
}

// ---------------- launch ----------------
extern "C" void kernel_launch(void* const* d_in, const int* in_sizes, int n_in,
                              void* d_out, int out_size, void* d_ws, size_t ws_size,
                              hipStream_t stream) {
  const float* x   = (const float*)d_in[0];
  const float* cqw = (const float*)d_in[1];
  const float* ckw = (const float*)d_in[2];
  const float* cvw = (const float*)d_in[3];
  const float* bqg = (const float*)d_in[4],  *bqb = (const float*)d_in[5];
  const float* bqm = (const float*)d_in[6],  *bqv = (const float*)d_in[7];
  const float* bkg = (const float*)d_in[8],  *bkb = (const float*)d_in[9];
  const float* bkm = (const float*)d_in[10], *bkv = (const float*)d_in[11];
  const float* bvg = (const float*)d_in[12], *bvb = (const float*)d_in[13];
  const float* bvm = (const float*)d_in[14], *bvv = (const float*)d_in[15];
  const float* wq = (const float*)d_in[16];
  const float* wk = (const float*)d_in[17];
  const float* wv = (const float*)d_in[18];
  const float* pw = (const float*)d_in[19];
  const float* pb = (const float*)d_in[20];

  f16* q_tok = (f16*)d_out;                              // lo half (25 MB)

  char* ws = (char*)d_ws;
  f16* wq_h  = (f16*)(ws + 0);
  f16* wk_h  = (f16*)(ws + 294912);
  f16* wv_h  = (f16*)(ws + 589824);
  f16* pw_h  = (f16*)(ws + 884736);
  f16* k_tok = (f16*)(ws + 1179648);
  f16* v_tok = (f16*)(ws + 4325376);
  f16* Kp    = (f16*)(ws + 7471104);
  f16* Vt    = (f16*)(ws + 10616832);
  f16* Oi    = (f16*)(ws + 13762560);
  float* wqT = (float*)(ws + 38928384);
  float* wkT = (float*)(ws + 38969856);
  float* wvT = (float*)(ws + 39011328);
  float* betq = (float*)(ws + 39052800);
  float* betk = (float*)(ws + 39054336);
  float* betv = (float*)(ws + 39055872);  // ws total 39,057,408 B

  const float scq = 0.051031036307982884f * 1.4426950408889634f; // 384^-0.5 * log2(e)
  cvt_w<<<dim3(576), dim3(256), 0, stream>>>(wq, wk, wv, pw, wq_h, wk_h, wv_h, pw_h,
                                             147456, scq);
  cvt_wt<<<dim3(27), dim3(384), 0, stream>>>(
      cqw, ckw, cvw,
      bqg, bqb, bqm, bqv, bkg, bkb, bkm, bkv, bvg, bvb, bvm, bvv,
      wqT, wkT, wvT, betq, betk, betv);
  conv_fused<<<dim3(192, 8, 4), dim3(128), 0, stream>>>(
      x, wqT, wkT, wvT, betq, betk, betv, q_tok, k_tok, v_tok);
  gemm_bt<0><<<dim3(3, 32),  dim3(256), 0, stream>>>(k_tok, wk_h, Kp, nullptr);
  gemm_bt<1><<<dim3(3, 32),  dim3(256), 0, stream>>>(v_tok, wv_h, Vt, nullptr);
  attn<<<dim3(32, 6, 8), dim3(256), 0, stream>>>(q_tok, wq_h, Kp, Vt, Oi);
  gemm_bt<2><<<dim3(3, 256), dim3(256), 0, stream>>>(Oi, pw_h, d_out, pb);
}

// Round 21
// 140.833 us; speedup vs baseline: 1.1894x; 1.0020x over previous
//
#include <hip/hip_runtime.h>
#include <hip/hip_bf16.h>
#include <stdint.h>

// Round 21: attn phase-1 repack via shfl_xor(32) instead of Qtmp LDS.
// Qtmp (18 KB, 4-way-conflicting) deleted: C-layout -> B-frag mapping is a
// pure lane<->lane+32 exchange (reg = (e&3)+4h+8(ks&1), producer lane (c,e>>2)).
// LDS 51200->32768 (5 blocks/CU cap), ~2M fewer bank conflicts, 1 less barrier.
// conv (R19) / K,V,out GEMMs / prep frozen.

typedef _Float16 f16;
typedef _Float16 f16x8 __attribute__((ext_vector_type(8)));
typedef float f32x4 __attribute__((ext_vector_type(4)));
typedef float f32x16 __attribute__((ext_vector_type(16)));
typedef uint32_t u32;
typedef uint32_t u32x4 __attribute__((ext_vector_type(4)));

#define NC 384
#define MFMA16(A_,B_,C_) __builtin_amdgcn_mfma_f32_16x16x32_f16((A_),(B_),(C_),0,0,0)
#define MFMA32(A_,B_,C_) __builtin_amdgcn_mfma_f32_32x32x16_f16((A_),(B_),(C_),0,0,0)

__device__ __forceinline__ void gll16(const void* g, void* l) {
  __builtin_amdgcn_global_load_lds(
      (__attribute__((address_space(1))) void*)g,
      (__attribute__((address_space(3))) void*)l, 16, 0, 0);
}

__device__ __forceinline__ u32 pkf16(float lo, float hi) {
  return __builtin_bit_cast(u32, __builtin_amdgcn_cvt_pkrtz(lo, hi));
}

// ---------------- weight fp32 -> f16 convert (scq folded into wq) ----------------
__global__ __launch_bounds__(256) void cvt_w(
    const float* __restrict__ s0, const float* __restrict__ s1,
    const float* __restrict__ s2, const float* __restrict__ s3,
    f16* __restrict__ d0, f16* __restrict__ d1,
    f16* __restrict__ d2, f16* __restrict__ d3, int n, float scq)
{
  int i = blockIdx.x * 256 + threadIdx.x;
  if (i < n) {
    d0[i] = (f16)(s0[i] * scq);
    d1[i] = (f16)s1[i]; d2[i] = (f16)s2[i]; d3[i] = (f16)s3[i];
  }
}

// ---------------- conv-weight transpose + BN fold ----------------
__global__ __launch_bounds__(384) void cvt_wt(
    const float* __restrict__ wq, const float* __restrict__ wk, const float* __restrict__ wv,
    const float* __restrict__ bqg, const float* __restrict__ bqb,
    const float* __restrict__ bqm, const float* __restrict__ bqv,
    const float* __restrict__ bkg, const float* __restrict__ bkb,
    const float* __restrict__ bkm, const float* __restrict__ bkv,
    const float* __restrict__ bvg, const float* __restrict__ bvb,
    const float* __restrict__ bvm, const float* __restrict__ bvv,
    float* __restrict__ qT, float* __restrict__ kT, float* __restrict__ vT,
    float* __restrict__ betq, float* __restrict__ betk, float* __restrict__ betv)
{
  const int c = threadIdx.x;
  const int t = blockIdx.x;   // 0..26
  const float invq = bqg[c] * rsqrtf(bqv[c] + 1e-5f);
  const float invk = bkg[c] * rsqrtf(bkv[c] + 1e-5f);
  const float invv = bvg[c] * rsqrtf(bvv[c] + 1e-5f);
  qT[t * 384 + c] = wq[c * 27 + t] * invq;
  kT[t * 384 + c] = wk[c * 27 + t] * invk;
  vT[t * 384 + c] = wv[c * 27 + t] * invv;
  if (t == 0) {
    betq[c] = bqb[c] - bqm[c] * invq;
    betk[c] = bkb[c] - bkm[c] * invk;
    betv[c] = bvb[c] - bvm[c] * invv;
  }
}

// ---------------- fused depthwise conv3d + BN (R19), z-chunk=4, 3-slot ring ----------------
__global__ __launch_bounds__(128) void conv_fused(
    const float* __restrict__ x,
    const float* __restrict__ wqT, const float* __restrict__ wkT, const float* __restrict__ wvT,
    const float* __restrict__ betq_, const float* __restrict__ betk_,
    const float* __restrict__ betv_,
    f16* __restrict__ qout, f16* __restrict__ kout, f16* __restrict__ vout)
{
  const int tile = blockIdx.x / 3, cthird = blockIdx.x % 3;
  const int c = cthird * 128 + threadIdx.x;
  const int th = tile >> 3, tw = tile & 7;
  const int b = blockIdx.y;
  const int z0 = blockIdx.z * 4;
  const int h0 = th * 2, w0 = tw * 2;

  float wqr[27], wkr[27], wvr[27];
#pragma unroll
  for (int t = 0; t < 27; ++t) {
    wqr[t] = wqT[t * 384 + c];
    wkr[t] = wkT[t * 384 + c];
    wvr[t] = wvT[t * 384 + c];
  }
  const float betq = betq_[c], betk = betk_[c], betv = betv_[c];

  bool hok[4], wok[4];
#pragma unroll
  for (int a = 0; a < 4; ++a) {
    hok[a] = (unsigned)(h0 - 1 + a) < 16u;
    wok[a] = (unsigned)(w0 - 1 + a) < 16u;
  }
  const float* xb = x + (size_t)b * 4096 * NC + c;

  float win[3][4][4];
  auto ldplane = [&](int s, int iz) {
    const bool zok = (unsigned)iz < 16u;
#pragma unroll
    for (int a = 0; a < 4; ++a)
#pragma unroll
      for (int e = 0; e < 4; ++e) {
        float v = 0.f;
        if (zok && hok[a] && wok[e])
          v = xb[(size_t)((h0 - 1 + a) * 256 + (w0 - 1 + e) * 16 + iz) * NC];
        win[s][a][e] = v;
      }
  };
  ldplane(0, z0 - 1);
  ldplane(1, z0);

#pragma unroll
  for (int zr = 0; zr < 4; ++zr) {
    const int z = z0 + zr;
    ldplane((zr + 2) % 3, z + 1);
    float aq00 = 0.f, aq01 = 0.f, aq10 = 0.f, aq11 = 0.f;
    float ak = 0.f, av = 0.f;
#pragma unroll
    for (int p = 0; p < 3; ++p) {
      const int s = (zr + p) % 3;
#pragma unroll
      for (int a = 0; a < 3; ++a)
#pragma unroll
        for (int e = 0; e < 3; ++e) {
          const float w00 = win[s][a][e],     w01 = win[s][a][e + 1];
          const float w10 = win[s][a + 1][e], w11 = win[s][a + 1][e + 1];
          const float cq = wqr[a * 9 + e * 3 + p];
          aq00 += w00 * cq; aq01 += w01 * cq;
          aq10 += w10 * cq; aq11 += w11 * cq;
          if ((zr & 1) == 0) {
            ak += w00 * wkr[a * 9 + e * 3 + p];
            av += w00 * wvr[a * 9 + e * 3 + p];
          }
        }
    }
    const size_t qb = (size_t)b * 4096;
    qout[(qb + (h0 + 0) * 256 + (w0 + 0) * 16 + z) * NC + c] = (f16)(aq00 + betq);
    qout[(qb + (h0 + 0) * 256 + (w0 + 1) * 16 + z) * NC + c] = (f16)(aq01 + betq);
    qout[(qb + (h0 + 1) * 256 + (w0 + 0) * 16 + z) * NC + c] = (f16)(aq10 + betq);
    qout[(qb + (h0 + 1) * 256 + (w0 + 1) * 16 + z) * NC + c] = (f16)(aq11 + betq);
    if ((zr & 1) == 0) {
      const size_t t = (size_t)b * 512 + tile * 8 + (z >> 1);
      kout[t * NC + c] = (f16)(ak + betk);
      vout[t * NC + c] = (f16)(av + betv);
    }
  }
}

// ---------------- GEMM (R8 version): gll16 staging + XOR-swizzled LDS ----------------
template<int MODE>
__global__ __launch_bounds__(256) void gemm_bt(
    const f16* __restrict__ A, const f16* __restrict__ Bw,
    void* __restrict__ Cout, const float* __restrict__ bias)
{
  __shared__ f16 As[128 * 64];
  __shared__ f16 Bs[128 * 64];
  const int tid = threadIdx.x;
  const int w = tid >> 6, lane = tid & 63;
  const int g = lane >> 4, q = lane & 15;
  const int wr = w >> 1, wc = w & 1;
  const size_t brow = (size_t)blockIdx.y * 128;
  const int bcol = blockIdx.x * 128;
  const int srow = lane >> 3;
  const int sbb  = (lane & 7) ^ (srow & 7);
  f32x4 acc[4][4] = {};
  for (int kt = 0; kt < 6; ++kt) {
    const int k0 = kt * 64;
#pragma unroll
    for (int j = 0; j < 4; ++j) {
      const int s = w * 4 + j;
      gll16(A  + (brow + (size_t)(s * 8 + srow)) * NC + k0 + sbb * 8, (char*)As + s * 1024);
      gll16(Bw + (size_t)(bcol + s * 8 + srow) * NC + k0 + sbb * 8, (char*)Bs + s * 1024);
    }
    __syncthreads();
#pragma unroll
    for (int ks = 0; ks < 2; ++ks) {
      f16x8 af[4], bfr[4];
      const int bb = ((g + 4 * ks) ^ (q & 7)) * 16;
#pragma unroll
      for (int m = 0; m < 4; ++m) {
        af[m]  = *(const f16x8*)((const char*)As + (wr * 64 + m * 16 + q) * 128 + bb);
        bfr[m] = *(const f16x8*)((const char*)Bs + (wc * 64 + m * 16 + q) * 128 + bb);
      }
#pragma unroll
      for (int m = 0; m < 4; ++m)
#pragma unroll
        for (int n = 0; n < 4; ++n)
          acc[m][n] = MFMA16(af[m], bfr[n], acc[m][n]);
    }
    __syncthreads();
  }
  float bvals[4];
  if (MODE == 2) {
#pragma unroll
    for (int n = 0; n < 4; ++n) bvals[n] = bias[bcol + wc * 64 + n * 16 + q];
  }
#pragma unroll
  for (int m = 0; m < 4; ++m) {
#pragma unroll
    for (int n = 0; n < 4; ++n) {
#pragma unroll
      for (int r = 0; r < 4; ++r) {
        const size_t row = brow + wr * 64 + m * 16 + 4 * g + r;
        const int col = bcol + wc * 64 + n * 16 + q;
        const float v = acc[m][n][r];
        if (MODE == 0) {
          ((f16*)Cout)[row * NC + col] = (f16)v;
        } else if (MODE == 1) {
          const size_t bi = row >> 9, t = row & 511;
          ((f16*)Cout)[(bi * NC + col) * 512 + t] = (f16)v;
        } else {
          ((float*)Cout)[row * NC + col] = v + bvals[n];
        }
      }
    }
  }
}

// ---------------- flash attention, fused Q-proj, shuffle repack ----------------
// grid (32 qtiles, 6 heads, 8 b); 256 thr = 4 waves x 32 q-rows.
__global__ __launch_bounds__(256) void attn(
    const f16* __restrict__ qtok, const f16* __restrict__ wqh,
    const f16* __restrict__ Kp, const f16* __restrict__ Vt, f16* __restrict__ O)
{
  __shared__ f16 Ks[2][64 * 64];   // phase1: q_tok tile staging (16 KB)
  __shared__ f16 Vs[2][64 * 64];   // Vs[1] = phase1 wq staging
  const int tid = threadIdx.x;
  const int w = tid >> 6, lane = tid & 63;
  const int c = lane & 31, h = lane >> 5;
  const int qt = blockIdx.x, hh = blockIdx.y, b = blockIdx.z;
  const size_t qrow0b = (size_t)b * 4096 + qt * 128;
  const size_t qrow = qrow0b + w * 32 + c;

  // staging addresses (phase 2)
  const int r0 = tid >> 3, k0b = tid & 7;
  const int r1 = (tid + 256) >> 3;
  const f16* ks0 = Kp + ((size_t)b * 512 + r0) * NC + hh * 64 + ((k0b ^ (r0 & 7)) * 8);
  const f16* ks1 = Kp + ((size_t)b * 512 + r1) * NC + hh * 64 + ((k0b ^ (r1 & 7)) * 8);
  const f16* vs0 = Vt + ((size_t)b * NC + hh * 64 + r0) * 512 + ((k0b ^ (r0 & 7)) * 8);
  const f16* vs1 = Vt + ((size_t)b * NC + hh * 64 + r1) * 512 + ((k0b ^ (r1 & 7)) * 8);
  gll16(vs0, (char*)&Vs[0][0] + tid * 16);          // V chunk 0 (Vs[0] untouched)
  gll16(vs1, (char*)&Vs[0][0] + (tid + 256) * 16);

  // ---- Phase 1: Q-projection (C layout: lane (c,h) holds Q[d][qrow=w*32+c]) ----
  f32x16 qa0 = {}, qa1 = {};
  {
    char* QsFlat = (char*)&Ks[0][0];   // 16 KB
    char* WqFlat = (char*)&Vs[1][0];   // 8 KB
    const int srow = lane >> 3, sbb = (lane & 7) ^ (srow & 7);
    for (int kt = 0; kt < 6; ++kt) {
#pragma unroll
      for (int j = 0; j < 4; ++j) {
        const int s = w * 4 + j;
        gll16(qtok + (qrow0b + (size_t)(s * 8 + srow)) * NC + kt * 64 + sbb * 8,
              QsFlat + s * 1024);
      }
#pragma unroll
      for (int j = 0; j < 2; ++j) {
        const int i = tid + j * 256;
        const int row = i >> 3, blk = i & 7;
        gll16(wqh + (size_t)(hh * 64 + row) * NC + kt * 64 + ((blk ^ (row & 7)) * 8),
              WqFlat + i * 16);
      }
      __syncthreads();
#pragma unroll
      for (int ks = 0; ks < 4; ++ks) {
        const int bo = ((2 * ks + h) ^ (c & 7)) * 16;
        const f16x8 bq = *(const f16x8*)(QsFlat + (w * 32 + c) * 128 + bo);
        const f16x8 a0 = *(const f16x8*)(WqFlat + c * 128 + bo);
        const f16x8 a1 = *(const f16x8*)(WqFlat + (32 + c) * 128 + bo);
        qa0 = MFMA32(a0, bq, qa0);
        qa1 = MFMA32(a1, bq, qa1);
      }
      __syncthreads();
    }
  }
  // Repack C-layout -> qf B-frags via lane<->lane+32 exchange.
  // qf[ks][e] = Q[d=16ks+8h+e][qrow]; producer lane (c, e>>2), reg (e&3)+4h+8(ks&1).
  f16x8 qf[4];
#pragma unroll
  for (int ks = 0; ks < 4; ++ks) {
    const int kb8 = 8 * (ks & 1);
    const f32x16 qa = (ks >> 1) ? qa1 : qa0;
    const u32 pk00 = pkf16(qa[kb8 + 0], qa[kb8 + 1]);
    const u32 pk01 = pkf16(qa[kb8 + 2], qa[kb8 + 3]);
    const u32 pk10 = pkf16(qa[kb8 + 4], qa[kb8 + 5]);
    const u32 pk11 = pkf16(qa[kb8 + 6], qa[kb8 + 7]);
    const u32 own_lo  = h ? pk10 : pk00;   // my regs at base 4h
    const u32 own_hi  = h ? pk11 : pk01;
    const u32 send_lo = h ? pk00 : pk10;   // partner needs base 4(h^1)
    const u32 send_hi = h ? pk01 : pk11;
    const u32 rl = __shfl_xor(send_lo, 32);
    const u32 rh = __shfl_xor(send_hi, 32);
    u32x4 fi;
    fi[0] = h ? rl : own_lo;
    fi[1] = h ? rh : own_hi;
    fi[2] = h ? own_lo : rl;
    fi[3] = h ? own_hi : rh;
    qf[ks] = __builtin_bit_cast(f16x8, fi);
  }
  // K chunk 0 prefetch (Ks free: last phase-1 barrier passed)
  gll16(ks0, (char*)&Ks[0][0] + tid * 16);
  gll16(ks1, (char*)&Ks[0][0] + (tid + 256) * 16);

  // ---- Phase 2: main loop ----
  f32x16 oa0 = {}, oa1 = {};
  float l_run = 0.f;
  int buf = 0;
  for (int ch = 0; ch < 8; ++ch) {
    __syncthreads();
    if (ch < 7) {
      gll16(ks0 + (size_t)(ch + 1) * 64 * NC, (char*)&Ks[buf ^ 1][0] + tid * 16);
      gll16(ks1 + (size_t)(ch + 1) * 64 * NC, (char*)&Ks[buf ^ 1][0] + (tid + 256) * 16);
      gll16(vs0 + (ch + 1) * 64, (char*)&Vs[buf ^ 1][0] + tid * 16);
      gll16(vs1 + (ch + 1) * 64, (char*)&Vs[buf ^ 1][0] + (tid + 256) * 16);
    }
    const char* kb = (const char*)&Ks[buf][0];
    const char* vb = (const char*)&Vs[buf][0];
#pragma unroll
    for (int half = 0; half < 2; ++half) {
      f32x16 st = {};
#pragma unroll
      for (int ks = 0; ks < 4; ++ks) {
        const int bo = ((2 * ks + h) ^ (c & 7)) * 16;
        const f16x8 kf = *(const f16x8*)(kb + (32 * half + c) * 128 + bo);
        st = MFMA32(kf, qf[ks], st);
      }
      u32 pk[8];
      float ps0 = 0.f, ps1 = 0.f;
#pragma unroll
      for (int t = 0; t < 8; ++t) {
        const float a0 = __builtin_amdgcn_exp2f(st[2 * t]);
        const float a1 = __builtin_amdgcn_exp2f(st[2 * t + 1]);
        ps0 += a0; ps1 += a1;
        pk[t] = pkf16(a0, a1);
      }
      l_run += ps0 + ps1;
#pragma unroll
      for (int ss = 0; ss < 2; ++ss) {
        const int s = half * 2 + ss, tb = ss * 4;
        const u32 xs = h ? pk[tb + 0] : pk[tb + 2];
        const u32 ys = h ? pk[tb + 1] : pk[tb + 3];
        const u32 rx = __shfl_xor(xs, 32);
        const u32 ry = __shfl_xor(ys, 32);
        u32x4 fi;
        fi[0] = h ? rx : pk[tb + 0];
        fi[1] = h ? ry : pk[tb + 1];
        fi[2] = h ? pk[tb + 2] : rx;
        fi[3] = h ? pk[tb + 3] : ry;
        const f16x8 pfrag = __builtin_bit_cast(f16x8, fi);
        const int bo = ((2 * s + h) ^ (c & 7)) * 16;
        const f16x8 v0 = *(const f16x8*)(vb + c * 128 + bo);
        const f16x8 v1 = *(const f16x8*)(vb + (32 + c) * 128 + bo);
        oa0 = MFMA32(v0, pfrag, oa0);
        oa1 = MFMA32(v1, pfrag, oa1);
      }
    }
    buf ^= 1;
  }
  const float ltot = l_run + __shfl_xor(l_run, 32);
  const float linv = 1.0f / ltot;
  f16* orow = O + qrow * NC + hh * 64;
#pragma unroll
  for (int dt = 0; dt < 2; ++dt) {
#pragma unroll
    for (int qd = 0; qd < 4; ++qd) {
      const float v0 = (dt ? oa1[4 * qd + 0] : oa0[4 * qd + 0]) * linv;
      const float v1 = (dt ? oa1[4 * qd + 1] : oa0[4 * qd + 1]) * linv;
      const float v2 = (dt ? oa1[4 * qd + 2] : oa0[4 * qd + 2]) * linv;
      const float v3 = (dt ? oa1[4 * qd + 3] : oa0[4 * qd + 3]) * linv;
      uint2 pr; pr.x = pkf16(v0, v1); pr.y = pkf16(v2, v3);
      *(uint2*)(orow + dt * 32 + 8 * qd + 4 * h) = pr;
    }
  }
}

// ---------------- launch ----------------
extern "C" void kernel_launch(void* const* d_in, const int* in_sizes, int n_in,
                              void* d_out, int out_size, void* d_ws, size_t ws_size,
                              hipStream_t stream) {
  const float* x   = (const float*)d_in[0];
  const float* cqw = (const float*)d_in[1];
  const float* ckw = (const float*)d_in[2];
  const float* cvw = (const float*)d_in[3];
  const float* bqg = (const float*)d_in[4],  *bqb = (const float*)d_in[5];
  const float* bqm = (const float*)d_in[6],  *bqv = (const float*)d_in[7];
  const float* bkg = (const float*)d_in[8],  *bkb = (const float*)d_in[9];
  const float* bkm = (const float*)d_in[10], *bkv = (const float*)d_in[11];
  const float* bvg = (const float*)d_in[12], *bvb = (const float*)d_in[13];
  const float* bvm = (const float*)d_in[14], *bvv = (const float*)d_in[15];
  const float* wq = (const float*)d_in[16];
  const float* wk = (const float*)d_in[17];
  const float* wv = (const float*)d_in[18];
  const float* pw = (const float*)d_in[19];
  const float* pb = (const float*)d_in[20];

  f16* q_tok = (f16*)d_out;                              // lo half (25 MB)

  char* ws = (char*)d_ws;
  f16* wq_h  = (f16*)(ws + 0);
  f16* wk_h  = (f16*)(ws + 294912);
  f16* wv_h  = (f16*)(ws + 589824);
  f16* pw_h  = (f16*)(ws + 884736);
  f16* k_tok = (f16*)(ws + 1179648);
  f16* v_tok = (f16*)(ws + 4325376);
  f16* Kp    = (f16*)(ws + 7471104);
  f16* Vt    = (f16*)(ws + 10616832);
  f16* Oi    = (f16*)(ws + 13762560);
  float* wqT = (float*)(ws + 38928384);
  float* wkT = (float*)(ws + 38969856);
  float* wvT = (float*)(ws + 39011328);
  float* betq = (float*)(ws + 39052800);
  float* betk = (float*)(ws + 39054336);
  float* betv = (float*)(ws + 39055872);  // ws total 39,057,408 B

  const float scq = 0.051031036307982884f * 1.4426950408889634f; // 384^-0.5 * log2(e)
  cvt_w<<<dim3(576), dim3(256), 0, stream>>>(wq, wk, wv, pw, wq_h, wk_h, wv_h, pw_h,
                                             147456, scq);
  cvt_wt<<<dim3(27), dim3(384), 0, stream>>>(
      cqw, ckw, cvw,
      bqg, bqb, bqm, bqv, bkg, bkb, bkm, bkv, bvg, bvb, bvm, bvv,
      wqT, wkT, wvT, betq, betk, betv);
  conv_fused<<<dim3(192, 8, 4), dim3(128), 0, stream>>>(
      x, wqT, wkT, wvT, betq, betk, betv, q_tok, k_tok, v_tok);
  gemm_bt<0><<<dim3(3, 32),  dim3(256), 0, stream>>>(k_tok, wk_h, Kp, nullptr);
  gemm_bt<1><<<dim3(3, 32),  dim3(256), 0, stream>>>(v_tok, wv_h, Vt, nullptr);
  attn<<<dim3(32, 6, 8), dim3(256), 0, stream>>>(q_tok, wq_h, Kp, Vt, Oi);
  gemm_bt<2><<<dim3(3, 256), dim3(256), 0, stream>>>(Oi, pw_h, d_out, pb);
}

// Round 22
// 137.299 us; speedup vs baseline: 1.2200x; 1.0257x over previous
//
#include <hip/hip_runtime.h>
#include <hip/hip_bf16.h>
#include <stdint.h>

// Round 22: merge K-proj and V-proj GEMMs into one dispatch (blockIdx.z picks
// path): each was 96 blocks / 256 CUs, latency-bound, serialized on-stream
// despite independence. 192 concurrent blocks = same work, ~half the time.
// conv (R19) / attn (R21) / out-GEMM / prep frozen.

typedef _Float16 f16;
typedef _Float16 f16x8 __attribute__((ext_vector_type(8)));
typedef float f32x4 __attribute__((ext_vector_type(4)));
typedef float f32x16 __attribute__((ext_vector_type(16)));
typedef uint32_t u32;
typedef uint32_t u32x4 __attribute__((ext_vector_type(4)));

#define NC 384
#define MFMA16(A_,B_,C_) __builtin_amdgcn_mfma_f32_16x16x32_f16((A_),(B_),(C_),0,0,0)
#define MFMA32(A_,B_,C_) __builtin_amdgcn_mfma_f32_32x32x16_f16((A_),(B_),(C_),0,0,0)

__device__ __forceinline__ void gll16(const void* g, void* l) {
  __builtin_amdgcn_global_load_lds(
      (__attribute__((address_space(1))) void*)g,
      (__attribute__((address_space(3))) void*)l, 16, 0, 0);
}

__device__ __forceinline__ u32 pkf16(float lo, float hi) {
  return __builtin_bit_cast(u32, __builtin_amdgcn_cvt_pkrtz(lo, hi));
}

// ---------------- weight fp32 -> f16 convert (scq folded into wq) ----------------
__global__ __launch_bounds__(256) void cvt_w(
    const float* __restrict__ s0, const float* __restrict__ s1,
    const float* __restrict__ s2, const float* __restrict__ s3,
    f16* __restrict__ d0, f16* __restrict__ d1,
    f16* __restrict__ d2, f16* __restrict__ d3, int n, float scq)
{
  int i = blockIdx.x * 256 + threadIdx.x;
  if (i < n) {
    d0[i] = (f16)(s0[i] * scq);
    d1[i] = (f16)s1[i]; d2[i] = (f16)s2[i]; d3[i] = (f16)s3[i];
  }
}

// ---------------- conv-weight transpose + BN fold ----------------
__global__ __launch_bounds__(384) void cvt_wt(
    const float* __restrict__ wq, const float* __restrict__ wk, const float* __restrict__ wv,
    const float* __restrict__ bqg, const float* __restrict__ bqb,
    const float* __restrict__ bqm, const float* __restrict__ bqv,
    const float* __restrict__ bkg, const float* __restrict__ bkb,
    const float* __restrict__ bkm, const float* __restrict__ bkv,
    const float* __restrict__ bvg, const float* __restrict__ bvb,
    const float* __restrict__ bvm, const float* __restrict__ bvv,
    float* __restrict__ qT, float* __restrict__ kT, float* __restrict__ vT,
    float* __restrict__ betq, float* __restrict__ betk, float* __restrict__ betv)
{
  const int c = threadIdx.x;
  const int t = blockIdx.x;   // 0..26
  const float invq = bqg[c] * rsqrtf(bqv[c] + 1e-5f);
  const float invk = bkg[c] * rsqrtf(bkv[c] + 1e-5f);
  const float invv = bvg[c] * rsqrtf(bvv[c] + 1e-5f);
  qT[t * 384 + c] = wq[c * 27 + t] * invq;
  kT[t * 384 + c] = wk[c * 27 + t] * invk;
  vT[t * 384 + c] = wv[c * 27 + t] * invv;
  if (t == 0) {
    betq[c] = bqb[c] - bqm[c] * invq;
    betk[c] = bkb[c] - bkm[c] * invk;
    betv[c] = bvb[c] - bvm[c] * invv;
  }
}

// ---------------- fused depthwise conv3d + BN (R19), z-chunk=4, 3-slot ring ----------------
__global__ __launch_bounds__(128) void conv_fused(
    const float* __restrict__ x,
    const float* __restrict__ wqT, const float* __restrict__ wkT, const float* __restrict__ wvT,
    const float* __restrict__ betq_, const float* __restrict__ betk_,
    const float* __restrict__ betv_,
    f16* __restrict__ qout, f16* __restrict__ kout, f16* __restrict__ vout)
{
  const int tile = blockIdx.x / 3, cthird = blockIdx.x % 3;
  const int c = cthird * 128 + threadIdx.x;
  const int th = tile >> 3, tw = tile & 7;
  const int b = blockIdx.y;
  const int z0 = blockIdx.z * 4;
  const int h0 = th * 2, w0 = tw * 2;

  float wqr[27], wkr[27], wvr[27];
#pragma unroll
  for (int t = 0; t < 27; ++t) {
    wqr[t] = wqT[t * 384 + c];
    wkr[t] = wkT[t * 384 + c];
    wvr[t] = wvT[t * 384 + c];
  }
  const float betq = betq_[c], betk = betk_[c], betv = betv_[c];

  bool hok[4], wok[4];
#pragma unroll
  for (int a = 0; a < 4; ++a) {
    hok[a] = (unsigned)(h0 - 1 + a) < 16u;
    wok[a] = (unsigned)(w0 - 1 + a) < 16u;
  }
  const float* xb = x + (size_t)b * 4096 * NC + c;

  float win[3][4][4];
  auto ldplane = [&](int s, int iz) {
    const bool zok = (unsigned)iz < 16u;
#pragma unroll
    for (int a = 0; a < 4; ++a)
#pragma unroll
      for (int e = 0; e < 4; ++e) {
        float v = 0.f;
        if (zok && hok[a] && wok[e])
          v = xb[(size_t)((h0 - 1 + a) * 256 + (w0 - 1 + e) * 16 + iz) * NC];
        win[s][a][e] = v;
      }
  };
  ldplane(0, z0 - 1);
  ldplane(1, z0);

#pragma unroll
  for (int zr = 0; zr < 4; ++zr) {
    const int z = z0 + zr;
    ldplane((zr + 2) % 3, z + 1);
    float aq00 = 0.f, aq01 = 0.f, aq10 = 0.f, aq11 = 0.f;
    float ak = 0.f, av = 0.f;
#pragma unroll
    for (int p = 0; p < 3; ++p) {
      const int s = (zr + p) % 3;
#pragma unroll
      for (int a = 0; a < 3; ++a)
#pragma unroll
        for (int e = 0; e < 3; ++e) {
          const float w00 = win[s][a][e],     w01 = win[s][a][e + 1];
          const float w10 = win[s][a + 1][e], w11 = win[s][a + 1][e + 1];
          const float cq = wqr[a * 9 + e * 3 + p];
          aq00 += w00 * cq; aq01 += w01 * cq;
          aq10 += w10 * cq; aq11 += w11 * cq;
          if ((zr & 1) == 0) {
            ak += w00 * wkr[a * 9 + e * 3 + p];
            av += w00 * wvr[a * 9 + e * 3 + p];
          }
        }
    }
    const size_t qb = (size_t)b * 4096;
    qout[(qb + (h0 + 0) * 256 + (w0 + 0) * 16 + z) * NC + c] = (f16)(aq00 + betq);
    qout[(qb + (h0 + 0) * 256 + (w0 + 1) * 16 + z) * NC + c] = (f16)(aq01 + betq);
    qout[(qb + (h0 + 1) * 256 + (w0 + 0) * 16 + z) * NC + c] = (f16)(aq10 + betq);
    qout[(qb + (h0 + 1) * 256 + (w0 + 1) * 16 + z) * NC + c] = (f16)(aq11 + betq);
    if ((zr & 1) == 0) {
      const size_t t = (size_t)b * 512 + tile * 8 + (z >> 1);
      kout[t * NC + c] = (f16)(ak + betk);
      vout[t * NC + c] = (f16)(av + betv);
    }
  }
}

// ---------------- merged K/V projection GEMM (blockIdx.z: 0=K MODE0, 1=V MODE1) ----------------
__global__ __launch_bounds__(256) void gemm_kv(
    const f16* __restrict__ kA, const f16* __restrict__ kB, f16* __restrict__ kC,
    const f16* __restrict__ vA, const f16* __restrict__ vB, f16* __restrict__ vC)
{
  const bool isV = (blockIdx.z != 0);
  const f16* __restrict__ A  = isV ? vA : kA;
  const f16* __restrict__ Bw = isV ? vB : kB;
  __shared__ f16 As[128 * 64];
  __shared__ f16 Bs[128 * 64];
  const int tid = threadIdx.x;
  const int w = tid >> 6, lane = tid & 63;
  const int g = lane >> 4, q = lane & 15;
  const int wr = w >> 1, wc = w & 1;
  const size_t brow = (size_t)blockIdx.y * 128;
  const int bcol = blockIdx.x * 128;
  const int srow = lane >> 3;
  const int sbb  = (lane & 7) ^ (srow & 7);
  f32x4 acc[4][4] = {};
  for (int kt = 0; kt < 6; ++kt) {
    const int k0 = kt * 64;
#pragma unroll
    for (int j = 0; j < 4; ++j) {
      const int s = w * 4 + j;
      gll16(A  + (brow + (size_t)(s * 8 + srow)) * NC + k0 + sbb * 8, (char*)As + s * 1024);
      gll16(Bw + (size_t)(bcol + s * 8 + srow) * NC + k0 + sbb * 8, (char*)Bs + s * 1024);
    }
    __syncthreads();
#pragma unroll
    for (int ks = 0; ks < 2; ++ks) {
      f16x8 af[4], bfr[4];
      const int bb = ((g + 4 * ks) ^ (q & 7)) * 16;
#pragma unroll
      for (int m = 0; m < 4; ++m) {
        af[m]  = *(const f16x8*)((const char*)As + (wr * 64 + m * 16 + q) * 128 + bb);
        bfr[m] = *(const f16x8*)((const char*)Bs + (wc * 64 + m * 16 + q) * 128 + bb);
      }
#pragma unroll
      for (int m = 0; m < 4; ++m)
#pragma unroll
        for (int n = 0; n < 4; ++n)
          acc[m][n] = MFMA16(af[m], bfr[n], acc[m][n]);
    }
    __syncthreads();
  }
#pragma unroll
  for (int m = 0; m < 4; ++m) {
#pragma unroll
    for (int n = 0; n < 4; ++n) {
#pragma unroll
      for (int r = 0; r < 4; ++r) {
        const size_t row = brow + wr * 64 + m * 16 + 4 * g + r;
        const int col = bcol + wc * 64 + n * 16 + q;
        const float v = acc[m][n][r];
        if (!isV) {
          kC[row * NC + col] = (f16)v;
        } else {
          const size_t bi = row >> 9, t = row & 511;
          vC[(bi * NC + col) * 512 + t] = (f16)v;
        }
      }
    }
  }
}

// ---------------- out-projection GEMM (fp32 out + bias) ----------------
__global__ __launch_bounds__(256) void gemm_out(
    const f16* __restrict__ A, const f16* __restrict__ Bw,
    float* __restrict__ Cout, const float* __restrict__ bias)
{
  __shared__ f16 As[128 * 64];
  __shared__ f16 Bs[128 * 64];
  const int tid = threadIdx.x;
  const int w = tid >> 6, lane = tid & 63;
  const int g = lane >> 4, q = lane & 15;
  const int wr = w >> 1, wc = w & 1;
  const size_t brow = (size_t)blockIdx.y * 128;
  const int bcol = blockIdx.x * 128;
  const int srow = lane >> 3;
  const int sbb  = (lane & 7) ^ (srow & 7);
  f32x4 acc[4][4] = {};
  for (int kt = 0; kt < 6; ++kt) {
    const int k0 = kt * 64;
#pragma unroll
    for (int j = 0; j < 4; ++j) {
      const int s = w * 4 + j;
      gll16(A  + (brow + (size_t)(s * 8 + srow)) * NC + k0 + sbb * 8, (char*)As + s * 1024);
      gll16(Bw + (size_t)(bcol + s * 8 + srow) * NC + k0 + sbb * 8, (char*)Bs + s * 1024);
    }
    __syncthreads();
#pragma unroll
    for (int ks = 0; ks < 2; ++ks) {
      f16x8 af[4], bfr[4];
      const int bb = ((g + 4 * ks) ^ (q & 7)) * 16;
#pragma unroll
      for (int m = 0; m < 4; ++m) {
        af[m]  = *(const f16x8*)((const char*)As + (wr * 64 + m * 16 + q) * 128 + bb);
        bfr[m] = *(const f16x8*)((const char*)Bs + (wc * 64 + m * 16 + q) * 128 + bb);
      }
#pragma unroll
      for (int m = 0; m < 4; ++m)
#pragma unroll
        for (int n = 0; n < 4; ++n)
          acc[m][n] = MFMA16(af[m], bfr[n], acc[m][n]);
    }
    __syncthreads();
  }
  float bvals[4];
#pragma unroll
  for (int n = 0; n < 4; ++n) bvals[n] = bias[bcol + wc * 64 + n * 16 + q];
#pragma unroll
  for (int m = 0; m < 4; ++m) {
#pragma unroll
    for (int n = 0; n < 4; ++n) {
#pragma unroll
      for (int r = 0; r < 4; ++r) {
        const size_t row = brow + wr * 64 + m * 16 + 4 * g + r;
        const int col = bcol + wc * 64 + n * 16 + q;
        Cout[row * NC + col] = acc[m][n][r] + bvals[n];
      }
    }
  }
}

// ---------------- flash attention (R21): fused Q-proj, shuffle repack ----------------
__global__ __launch_bounds__(256) void attn(
    const f16* __restrict__ qtok, const f16* __restrict__ wqh,
    const f16* __restrict__ Kp, const f16* __restrict__ Vt, f16* __restrict__ O)
{
  __shared__ f16 Ks[2][64 * 64];
  __shared__ f16 Vs[2][64 * 64];
  const int tid = threadIdx.x;
  const int w = tid >> 6, lane = tid & 63;
  const int c = lane & 31, h = lane >> 5;
  const int qt = blockIdx.x, hh = blockIdx.y, b = blockIdx.z;
  const size_t qrow0b = (size_t)b * 4096 + qt * 128;
  const size_t qrow = qrow0b + w * 32 + c;

  const int r0 = tid >> 3, k0b = tid & 7;
  const int r1 = (tid + 256) >> 3;
  const f16* ks0 = Kp + ((size_t)b * 512 + r0) * NC + hh * 64 + ((k0b ^ (r0 & 7)) * 8);
  const f16* ks1 = Kp + ((size_t)b * 512 + r1) * NC + hh * 64 + ((k0b ^ (r1 & 7)) * 8);
  const f16* vs0 = Vt + ((size_t)b * NC + hh * 64 + r0) * 512 + ((k0b ^ (r0 & 7)) * 8);
  const f16* vs1 = Vt + ((size_t)b * NC + hh * 64 + r1) * 512 + ((k0b ^ (r1 & 7)) * 8);
  gll16(vs0, (char*)&Vs[0][0] + tid * 16);
  gll16(vs1, (char*)&Vs[0][0] + (tid + 256) * 16);

  // ---- Phase 1: Q-projection ----
  f32x16 qa0 = {}, qa1 = {};
  {
    char* QsFlat = (char*)&Ks[0][0];
    char* WqFlat = (char*)&Vs[1][0];
    const int srow = lane >> 3, sbb = (lane & 7) ^ (srow & 7);
    for (int kt = 0; kt < 6; ++kt) {
#pragma unroll
      for (int j = 0; j < 4; ++j) {
        const int s = w * 4 + j;
        gll16(qtok + (qrow0b + (size_t)(s * 8 + srow)) * NC + kt * 64 + sbb * 8,
              QsFlat + s * 1024);
      }
#pragma unroll
      for (int j = 0; j < 2; ++j) {
        const int i = tid + j * 256;
        const int row = i >> 3, blk = i & 7;
        gll16(wqh + (size_t)(hh * 64 + row) * NC + kt * 64 + ((blk ^ (row & 7)) * 8),
              WqFlat + i * 16);
      }
      __syncthreads();
#pragma unroll
      for (int ks = 0; ks < 4; ++ks) {
        const int bo = ((2 * ks + h) ^ (c & 7)) * 16;
        const f16x8 bq = *(const f16x8*)(QsFlat + (w * 32 + c) * 128 + bo);
        const f16x8 a0 = *(const f16x8*)(WqFlat + c * 128 + bo);
        const f16x8 a1 = *(const f16x8*)(WqFlat + (32 + c) * 128 + bo);
        qa0 = MFMA32(a0, bq, qa0);
        qa1 = MFMA32(a1, bq, qa1);
      }
      __syncthreads();
    }
  }
  // Repack C-layout -> qf B-frags via lane<->lane+32 exchange.
  f16x8 qf[4];
#pragma unroll
  for (int ks = 0; ks < 4; ++ks) {
    const int kb8 = 8 * (ks & 1);
    const f32x16 qa = (ks >> 1) ? qa1 : qa0;
    const u32 pk00 = pkf16(qa[kb8 + 0], qa[kb8 + 1]);
    const u32 pk01 = pkf16(qa[kb8 + 2], qa[kb8 + 3]);
    const u32 pk10 = pkf16(qa[kb8 + 4], qa[kb8 + 5]);
    const u32 pk11 = pkf16(qa[kb8 + 6], qa[kb8 + 7]);
    const u32 own_lo  = h ? pk10 : pk00;
    const u32 own_hi  = h ? pk11 : pk01;
    const u32 send_lo = h ? pk00 : pk10;
    const u32 send_hi = h ? pk01 : pk11;
    const u32 rl = __shfl_xor(send_lo, 32);
    const u32 rh = __shfl_xor(send_hi, 32);
    u32x4 fi;
    fi[0] = h ? rl : own_lo;
    fi[1] = h ? rh : own_hi;
    fi[2] = h ? own_lo : rl;
    fi[3] = h ? own_hi : rh;
    qf[ks] = __builtin_bit_cast(f16x8, fi);
  }
  gll16(ks0, (char*)&Ks[0][0] + tid * 16);
  gll16(ks1, (char*)&Ks[0][0] + (tid + 256) * 16);

  // ---- Phase 2: main loop ----
  f32x16 oa0 = {}, oa1 = {};
  float l_run = 0.f;
  int buf = 0;
  for (int ch = 0; ch < 8; ++ch) {
    __syncthreads();
    if (ch < 7) {
      gll16(ks0 + (size_t)(ch + 1) * 64 * NC, (char*)&Ks[buf ^ 1][0] + tid * 16);
      gll16(ks1 + (size_t)(ch + 1) * 64 * NC, (char*)&Ks[buf ^ 1][0] + (tid + 256) * 16);
      gll16(vs0 + (ch + 1) * 64, (char*)&Vs[buf ^ 1][0] + tid * 16);
      gll16(vs1 + (ch + 1) * 64, (char*)&Vs[buf ^ 1][0] + (tid + 256) * 16);
    }
    const char* kb = (const char*)&Ks[buf][0];
    const char* vb = (const char*)&Vs[buf][0];
#pragma unroll
    for (int half = 0; half < 2; ++half) {
      f32x16 st = {};
#pragma unroll
      for (int ks = 0; ks < 4; ++ks) {
        const int bo = ((2 * ks + h) ^ (c & 7)) * 16;
        const f16x8 kf = *(const f16x8*)(kb + (32 * half + c) * 128 + bo);
        st = MFMA32(kf, qf[ks], st);
      }
      u32 pk[8];
      float ps0 = 0.f, ps1 = 0.f;
#pragma unroll
      for (int t = 0; t < 8; ++t) {
        const float a0 = __builtin_amdgcn_exp2f(st[2 * t]);
        const float a1 = __builtin_amdgcn_exp2f(st[2 * t + 1]);
        ps0 += a0; ps1 += a1;
        pk[t] = pkf16(a0, a1);
      }
      l_run += ps0 + ps1;
#pragma unroll
      for (int ss = 0; ss < 2; ++ss) {
        const int s = half * 2 + ss, tb = ss * 4;
        const u32 xs = h ? pk[tb + 0] : pk[tb + 2];
        const u32 ys = h ? pk[tb + 1] : pk[tb + 3];
        const u32 rx = __shfl_xor(xs, 32);
        const u32 ry = __shfl_xor(ys, 32);
        u32x4 fi;
        fi[0] = h ? rx : pk[tb + 0];
        fi[1] = h ? ry : pk[tb + 1];
        fi[2] = h ? pk[tb + 2] : rx;
        fi[3] = h ? pk[tb + 3] : ry;
        const f16x8 pfrag = __builtin_bit_cast(f16x8, fi);
        const int bo = ((2 * s + h) ^ (c & 7)) * 16;
        const f16x8 v0 = *(const f16x8*)(vb + c * 128 + bo);
        const f16x8 v1 = *(const f16x8*)(vb + (32 + c) * 128 + bo);
        oa0 = MFMA32(v0, pfrag, oa0);
        oa1 = MFMA32(v1, pfrag, oa1);
      }
    }
    buf ^= 1;
  }
  const float ltot = l_run + __shfl_xor(l_run, 32);
  const float linv = 1.0f / ltot;
  f16* orow = O + qrow * NC + hh * 64;
#pragma unroll
  for (int dt = 0; dt < 2; ++dt) {
#pragma unroll
    for (int qd = 0; qd < 4; ++qd) {
      const float v0 = (dt ? oa1[4 * qd + 0] : oa0[4 * qd + 0]) * linv;
      const float v1 = (dt ? oa1[4 * qd + 1] : oa0[4 * qd + 1]) * linv;
      const float v2 = (dt ? oa1[4 * qd + 2] : oa0[4 * qd + 2]) * linv;
      const float v3 = (dt ? oa1[4 * qd + 3] : oa0[4 * qd + 3]) * linv;
      uint2 pr; pr.x = pkf16(v0, v1); pr.y = pkf16(v2, v3);
      *(uint2*)(orow + dt * 32 + 8 * qd + 4 * h) = pr;
    }
  }
}

// ---------------- launch ----------------
extern "C" void kernel_launch(void* const* d_in, const int* in_sizes, int n_in,
                              void* d_out, int out_size, void* d_ws, size_t ws_size,
                              hipStream_t stream) {
  const float* x   = (const float*)d_in[0];
  const float* cqw = (const float*)d_in[1];
  const float* ckw = (const float*)d_in[2];
  const float* cvw = (const float*)d_in[3];
  const float* bqg = (const float*)d_in[4],  *bqb = (const float*)d_in[5];
  const float* bqm = (const float*)d_in[6],  *bqv = (const float*)d_in[7];
  const float* bkg = (const float*)d_in[8],  *bkb = (const float*)d_in[9];
  const float* bkm = (const float*)d_in[10], *bkv = (const float*)d_in[11];
  const float* bvg = (const float*)d_in[12], *bvb = (const float*)d_in[13];
  const float* bvm = (const float*)d_in[14], *bvv = (const float*)d_in[15];
  const float* wq = (const float*)d_in[16];
  const float* wk = (const float*)d_in[17];
  const float* wv = (const float*)d_in[18];
  const float* pw = (const float*)d_in[19];
  const float* pb = (const float*)d_in[20];

  f16* q_tok = (f16*)d_out;                              // lo half (25 MB)

  char* ws = (char*)d_ws;
  f16* wq_h  = (f16*)(ws + 0);
  f16* wk_h  = (f16*)(ws + 294912);
  f16* wv_h  = (f16*)(ws + 589824);
  f16* pw_h  = (f16*)(ws + 884736);
  f16* k_tok = (f16*)(ws + 1179648);
  f16* v_tok = (f16*)(ws + 4325376);
  f16* Kp    = (f16*)(ws + 7471104);
  f16* Vt    = (f16*)(ws + 10616832);
  f16* Oi    = (f16*)(ws + 13762560);
  float* wqT = (float*)(ws + 38928384);
  float* wkT = (float*)(ws + 38969856);
  float* wvT = (float*)(ws + 39011328);
  float* betq = (float*)(ws + 39052800);
  float* betk = (float*)(ws + 39054336);
  float* betv = (float*)(ws + 39055872);  // ws total 39,057,408 B

  const float scq = 0.051031036307982884f * 1.4426950408889634f; // 384^-0.5 * log2(e)
  cvt_w<<<dim3(576), dim3(256), 0, stream>>>(wq, wk, wv, pw, wq_h, wk_h, wv_h, pw_h,
                                             147456, scq);
  cvt_wt<<<dim3(27), dim3(384), 0, stream>>>(
      cqw, ckw, cvw,
      bqg, bqb, bqm, bqv, bkg, bkb, bkm, bkv, bvg, bvb, bvm, bvv,
      wqT, wkT, wvT, betq, betk, betv);
  conv_fused<<<dim3(192, 8, 4), dim3(128), 0, stream>>>(
      x, wqT, wkT, wvT, betq, betk, betv, q_tok, k_tok, v_tok);
  gemm_kv<<<dim3(3, 32, 2), dim3(256), 0, stream>>>(
      k_tok, wk_h, Kp, v_tok, wv_h, Vt);
  attn<<<dim3(32, 6, 8), dim3(256), 0, stream>>>(q_tok, wq_h, Kp, Vt, Oi);
  gemm_out<<<dim3(3, 256), dim3(256), 0, stream>>>(Oi, pw_h, (float*)d_out, pb);
}